// Round 1
// baseline (7392.718 us; speedup 1.0000x reference)
//
#include <hip/hip_runtime.h>

#define NW 512      // Bn windows
#define WT 128      // tokens per window
#define DM 768      // model dim
#define HD 64       // head dim
#define NH 12       // heads

// ---------------- kernel 1 LDS layout (float offsets) ----------------
// qs[128][68], ks[128][68], vs[128][68]  (stride 68 -> 272B, 16B aligned, pad vs banks)
// xb[128][36], wb[192][36] staging for QKV GEMM
// bias[192]
// P[128][132] overlays qs+ks after scores are consumed
#define ST_Q   0
#define ST_K   8704
#define ST_V   17408
#define ST_XB  26112
#define ST_WB  30720
#define ST_BIA 37632
#define LDS_K1 37824      // 151296 bytes  (<= 160 KiB)
#define ST_P   0

__device__ __forceinline__ float fma4(float4 a, float4 b, float c) {
  c = fmaf(a.x, b.x, c);
  c = fmaf(a.y, b.y, c);
  c = fmaf(a.z, b.z, c);
  c = fmaf(a.w, b.w, c);
  return c;
}

__global__ __launch_bounds__(512) void attn_kernel(
    const float* __restrict__ x, const float* __restrict__ qkv_w,
    const float* __restrict__ qkv_b, const float* __restrict__ edge_bias,
    const float* __restrict__ mask, float* __restrict__ out)
{
  __shared__ float lds[LDS_K1];
  const int t  = threadIdx.x;
  const int h  = blockIdx.x;      // head
  const int bn = blockIdx.y;      // window
  const int fw = bn & 127;        // bn % (f*w)
  const float* xw = x + (size_t)bn * (WT * DM);
  const float* mk = mask + (size_t)fw * (WT * WT);
  const float* eb = edge_bias + (size_t)h * (WT * WT);

  // preload bias slice for this head (q,k,v sections)
  if (t < 192) {
    int sec = t >> 6, d = t & 63;
    lds[ST_BIA + t] = qkv_b[sec * DM + h * HD + d];
  }

  // ---------------- Phase A: qkv_head[128][192] = xw[128][768] @ Wh^T ----------
  const int tr = t >> 5;          // 0..15 : rows tr*8 .. +8
  const int tc = t & 31;          // 0..31 : cols tc*6 .. +6
  float acc[8][6];
#pragma unroll
  for (int i = 0; i < 8; ++i)
#pragma unroll
    for (int j = 0; j < 6; ++j) acc[i][j] = 0.f;

  for (int kc = 0; kc < DM; kc += 32) {
    // stage x block [128][32]
#pragma unroll
    for (int q = 0; q < 2; ++q) {
      int fid = q * 512 + t;                 // 0..1023 float4 ids
      int r = fid >> 3, c4 = fid & 7;
      float4 v = *(const float4*)(xw + r * DM + kc + c4 * 4);
      *(float4*)(&lds[ST_XB + r * 36 + c4 * 4]) = v;
    }
    // stage W block [192][32]; W rows: sec*768 + h*64 + d
#pragma unroll
    for (int q = 0; q < 3; ++q) {
      int fid = q * 512 + t;                 // 0..1535
      int j = fid >> 3, c4 = fid & 7;
      int g = (j >> 6) * DM + h * HD + (j & 63);
      float4 v = *(const float4*)(qkv_w + (size_t)g * DM + kc + c4 * 4);
      *(float4*)(&lds[ST_WB + j * 36 + c4 * 4]) = v;
    }
    __syncthreads();
#pragma unroll
    for (int k4 = 0; k4 < 8; ++k4) {
      float4 a4[8], b4[6];
#pragma unroll
      for (int i = 0; i < 8; ++i)
        a4[i] = *(const float4*)(&lds[ST_XB + (tr * 8 + i) * 36 + k4 * 4]);
#pragma unroll
      for (int j = 0; j < 6; ++j)
        b4[j] = *(const float4*)(&lds[ST_WB + (tc * 6 + j) * 36 + k4 * 4]);
#pragma unroll
      for (int i = 0; i < 8; ++i)
#pragma unroll
        for (int j = 0; j < 6; ++j)
          acc[i][j] = fma4(a4[i], b4[j], acc[i][j]);
    }
    __syncthreads();
  }

  // scatter to qs (scaled), ks, vs
#pragma unroll
  for (int i = 0; i < 8; ++i) {
    int r = tr * 8 + i;
#pragma unroll
    for (int j = 0; j < 6; ++j) {
      int c = tc * 6 + j;
      float v = acc[i][j] + lds[ST_BIA + c];
      if (c < 64)       lds[ST_Q + r * 68 + c]         = v * 0.125f;  // q * hd^-0.5
      else if (c < 128) lds[ST_K + r * 68 + (c - 64)]  = v;
      else              lds[ST_V + r * 68 + (c - 128)] = v;
    }
  }
  __syncthreads();

  // ---------------- Phase B: S[128][128] = q @ k^T (registers) -----------------
  const int tr2 = t >> 4;         // 0..31 : rows tr2*4 .. +4
  const int tc2 = t & 15;         // cols tc2 + 16*j
  float s[4][8];
#pragma unroll
  for (int i = 0; i < 4; ++i)
#pragma unroll
    for (int j = 0; j < 8; ++j) s[i][j] = 0.f;

#pragma unroll 4
  for (int d4 = 0; d4 < 16; ++d4) {
    float4 qv[4], kv[8];
#pragma unroll
    for (int i = 0; i < 4; ++i)
      qv[i] = *(const float4*)(&lds[ST_Q + (tr2 * 4 + i) * 68 + d4 * 4]);
#pragma unroll
    for (int j = 0; j < 8; ++j)
      kv[j] = *(const float4*)(&lds[ST_K + (tc2 + 16 * j) * 68 + d4 * 4]);
#pragma unroll
    for (int i = 0; i < 4; ++i)
#pragma unroll
      for (int j = 0; j < 8; ++j)
        s[i][j] = fma4(qv[i], kv[j], s[i][j]);
  }
  __syncthreads();   // q,k consumed; P may overlay them now

  // ---------------- Phase C: softmax -> prune -> mask/bias -> softmax ----------
#pragma unroll
  for (int i = 0; i < 4; ++i) {
    int r = tr2 * 4 + i;
    float m1 = s[i][0];
#pragma unroll
    for (int j = 1; j < 8; ++j) m1 = fmaxf(m1, s[i][j]);
#pragma unroll
    for (int off = 1; off < 16; off <<= 1) m1 = fmaxf(m1, __shfl_xor(m1, off, 64));
    float e[8], sum1 = 0.f;
#pragma unroll
    for (int j = 0; j < 8; ++j) { e[j] = __expf(s[i][j] - m1); sum1 += e[j]; }
#pragma unroll
    for (int off = 1; off < 16; off <<= 1) sum1 += __shfl_xor(sum1, off, 64);
    float thr = 0.5f * sum1;                 // probs > 0.5  <=>  e > 0.5*sum1
    float tv[8];
#pragma unroll
    for (int j = 0; j < 8; ++j) {
      int c = tc2 + 16 * j;
      float keep = (e[j] > thr) ? 0.f : 1.f;
      float val = s[i][j] * keep * mk[r * WT + c] * eb[r * WT + c];
      tv[j] = (val == 0.f) ? -10000.f : val;
    }
    float m2 = tv[0];
#pragma unroll
    for (int j = 1; j < 8; ++j) m2 = fmaxf(m2, tv[j]);
#pragma unroll
    for (int off = 1; off < 16; off <<= 1) m2 = fmaxf(m2, __shfl_xor(m2, off, 64));
    float e2[8], sum2 = 0.f;
#pragma unroll
    for (int j = 0; j < 8; ++j) { e2[j] = __expf(tv[j] - m2); sum2 += e2[j]; }
#pragma unroll
    for (int off = 1; off < 16; off <<= 1) sum2 += __shfl_xor(sum2, off, 64);
    float inv = 1.f / sum2;
#pragma unroll
    for (int j = 0; j < 8; ++j)
      lds[ST_P + r * 132 + tc2 + 16 * j] = e2[j] * inv;
  }
  __syncthreads();

  // ---------------- Phase D: out_head[128][64] = P @ v -------------------------
  float o[4][4];
#pragma unroll
  for (int i = 0; i < 4; ++i)
#pragma unroll
    for (int l = 0; l < 4; ++l) o[i][l] = 0.f;

#pragma unroll 4
  for (int c4 = 0; c4 < 32; ++c4) {
    float pf[4][4];
#pragma unroll
    for (int i = 0; i < 4; ++i) {
      float4 pv = *(const float4*)(&lds[ST_P + (tr2 * 4 + i) * 132 + c4 * 4]);
      pf[i][0] = pv.x; pf[i][1] = pv.y; pf[i][2] = pv.z; pf[i][3] = pv.w;
    }
#pragma unroll
    for (int cc = 0; cc < 4; ++cc) {
      float4 vv = *(const float4*)(&lds[ST_V + (c4 * 4 + cc) * 68 + tc2 * 4]);
      float vvf[4] = {vv.x, vv.y, vv.z, vv.w};
#pragma unroll
      for (int i = 0; i < 4; ++i)
#pragma unroll
        for (int l = 0; l < 4; ++l)
          o[i][l] = fmaf(pf[i][cc], vvf[l], o[i][l]);
    }
  }

  // write [bn][r][h*64 + d]  (transpose(0,2,1,3).reshape layout)
#pragma unroll
  for (int i = 0; i < 4; ++i) {
    int r = tr2 * 4 + i;
    float4 res = make_float4(o[i][0], o[i][1], o[i][2], o[i][3]);
    *(float4*)(out + (size_t)bn * (WT * DM) + r * DM + h * HD + tc2 * 4) = res;
  }
}

// ---------------- kernel 2: proj GEMM, safe in-place per-16-row block ----------
__global__ __launch_bounds__(256) void proj_kernel(
    const float* src, const float* __restrict__ pw,
    const float* __restrict__ pb, float* dst)
{
  __shared__ float a[16 * 772];    // own 16 rows, staged before overwrite
  __shared__ float wb[8 * 772];    // transposed W chunk: wb[kk][n]
  const int t = threadIdx.x;
  const size_t row0 = (size_t)blockIdx.x * 16;

  // stage this block's 16 rows (768 floats each)
#pragma unroll
  for (int q = 0; q < 12; ++q) {
    int fid = q * 256 + t;               // 0..3071 float4 ids, 192 per row
    int r = fid / 192;
    int c4 = fid - r * 192;
    float4 v = *(const float4*)(src + (row0 + r) * DM + c4 * 4);
    *(float4*)(&a[r * 772 + c4 * 4]) = v;
  }
  __syncthreads();

  const int wr = t >> 6;               // 0..3 : rows wr*4 .. +4
  const int wc = t & 63;               // cols wc*4 + 256*jj
  float accp[4][12];
#pragma unroll
  for (int i = 0; i < 4; ++i)
#pragma unroll
    for (int j = 0; j < 12; ++j) accp[i][j] = 0.f;

  for (int kc = 0; kc < DM; kc += 8) {
    // stage wb[kk][n] = pw[n][kc+kk] for all n
#pragma unroll
    for (int q = 0; q < 6; ++q) {
      int fid = q * 256 + t;             // 0..1535
      int n = fid >> 1, h4 = fid & 1;
      float4 v = *(const float4*)(pw + (size_t)n * DM + kc + h4 * 4);
      wb[(h4 * 4 + 0) * 772 + n] = v.x;
      wb[(h4 * 4 + 1) * 772 + n] = v.y;
      wb[(h4 * 4 + 2) * 772 + n] = v.z;
      wb[(h4 * 4 + 3) * 772 + n] = v.w;
    }
    __syncthreads();
#pragma unroll
    for (int kk = 0; kk < 8; ++kk) {
      float av[4];
#pragma unroll
      for (int i = 0; i < 4; ++i) av[i] = a[(wr * 4 + i) * 772 + kc + kk];
      float4 b0 = *(const float4*)(&wb[kk * 772 + wc * 4]);
      float4 b1 = *(const float4*)(&wb[kk * 772 + wc * 4 + 256]);
      float4 b2 = *(const float4*)(&wb[kk * 772 + wc * 4 + 512]);
      float bf[12] = {b0.x, b0.y, b0.z, b0.w, b1.x, b1.y, b1.z, b1.w,
                      b2.x, b2.y, b2.z, b2.w};
#pragma unroll
      for (int i = 0; i < 4; ++i)
#pragma unroll
        for (int j = 0; j < 12; ++j)
          accp[i][j] = fmaf(av[i], bf[j], accp[i][j]);
    }
    __syncthreads();
  }

  // epilogue: + bias, store (overwrites only this block's own rows)
#pragma unroll
  for (int i = 0; i < 4; ++i) {
    size_t r = row0 + wr * 4 + i;
#pragma unroll
    for (int jj = 0; jj < 3; ++jj) {
      int c = wc * 4 + jj * 256;
      float4 bias = *(const float4*)(pb + c);
      float4 res = make_float4(accp[i][jj * 4 + 0] + bias.x,
                               accp[i][jj * 4 + 1] + bias.y,
                               accp[i][jj * 4 + 2] + bias.z,
                               accp[i][jj * 4 + 3] + bias.w);
      *(float4*)(dst + r * DM + c) = res;
    }
  }
}

extern "C" void kernel_launch(void* const* d_in, const int* in_sizes, int n_in,
                              void* d_out, int out_size, void* d_ws, size_t ws_size,
                              hipStream_t stream) {
  const float* x         = (const float*)d_in[0];
  const float* qkv_w     = (const float*)d_in[1];
  const float* qkv_b     = (const float*)d_in[2];
  const float* proj_w    = (const float*)d_in[3];
  const float* proj_b    = (const float*)d_in[4];
  const float* edge_bias = (const float*)d_in[5];
  const float* mask      = (const float*)d_in[6];
  float* out = (float*)d_out;

  dim3 g1(NH, NW);   // heads fastest: 12 heads of one window adjacent for L2 reuse of x
  attn_kernel<<<g1, 512, 0, stream>>>(x, qkv_w, qkv_b, edge_bias, mask, out);
  proj_kernel<<<NW * WT / 16, 256, 0, stream>>>(out, proj_w, proj_b, out);
}

// Round 2
// 1573.601 us; speedup vs baseline: 4.6980x; 4.6980x over previous
//
#include <hip/hip_runtime.h>

#define NW 512
#define WT 128
#define DM 768
#define NH 12

typedef __attribute__((ext_vector_type(8))) short bf16x8;
typedef __attribute__((ext_vector_type(4))) float f32x4;

__device__ __forceinline__ unsigned short bf_rne(float v) {
  unsigned u = __float_as_uint(v);
  unsigned r = u + 0x7fffu + ((u >> 16) & 1u);
  return (unsigned short)(r >> 16);
}
__device__ __forceinline__ void bf_split(float v, unsigned short& hi, unsigned short& lo) {
  hi = bf_rne(v);
  float hf = __uint_as_float(((unsigned)hi) << 16);
  lo = bf_rne(v - hf);
}

// ---------------- attn kernel LDS layout (bytes) ----------------
// Phase A staging: Wbuf[2] { hi[192][64]bf16 swz, lo[192][64] } @ b*49152
// Post-A: Q_HI@0 Q_LO@16384 K_HI@32768 K_LO@49152 (each [128][64]bf16 swz)
//         VT@65536: [64][272B] bf16 (128 tok + pad)
//         P@0: [128][272B] bf16 (overlays q/k after they are dead)
#define QH_OFF 0
#define QL_OFF 16384
#define KH_OFF 32768
#define KL_OFF 49152
#define VT_OFF 65536
#define P_OFF  0
#define SM_ATTN 98304

__global__ __launch_bounds__(512, 2) void attn_kernel(
    const float* __restrict__ x, const float* __restrict__ qkv_w,
    const float* __restrict__ qkv_b, const float* __restrict__ edge_bias,
    const float* __restrict__ mask, float* __restrict__ out)
{
  __shared__ __align__(16) unsigned char smem[SM_ATTN];
  const int t = threadIdx.x;
  const int lane = t & 63;
  const int w = t >> 6;          // 0..7
  const int g = lane >> 4;       // 0..3
  const int ln = lane & 15;      // 0..15
  const int wm = w & 3;          // m-block (32 rows)
  const int wn = w >> 2;         // n-half (96 cols)

  const int orig = blockIdx.x;
  const int wg = (orig & 7) * 768 + (orig >> 3);   // XCD-contiguous, bijective
  const int h = wg % 12;
  const int bn = wg / 12;

  const float* xw = x + (size_t)bn * (WT * DM);

  f32x4 acc[2][6];
#pragma unroll
  for (int i = 0; i < 2; ++i)
#pragma unroll
    for (int j = 0; j < 6; ++j) acc[i][j] = (f32x4){0.f, 0.f, 0.f, 0.f};

  float4 wreg[6], xreg[8];
  // prologue W load (chunk 0)
#pragma unroll
  for (int q = 0; q < 6; ++q) {
    int fid = q * 512 + t;
    int j = fid >> 4, c4 = fid & 15;
    int sec = j >> 6, d = j & 63;
    wreg[q] = *(const float4*)(qkv_w + (size_t)(sec * DM + h * 64 + d) * DM + c4 * 4);
  }

  for (int c = 0; c < 12; ++c) {
    const int kc = c * 64;
    // issue x loads for this chunk (A-operand, global->reg)
#pragma unroll
    for (int sm = 0; sm < 2; ++sm)
#pragma unroll
      for (int ks = 0; ks < 2; ++ks) {
        int row = wm * 32 + sm * 16 + ln;
        const float* p = xw + (size_t)row * DM + kc + ks * 32 + g * 8;
        xreg[(sm * 2 + ks) * 2 + 0] = *(const float4*)p;
        xreg[(sm * 2 + ks) * 2 + 1] = *(const float4*)(p + 4);
      }
    // stage W chunk c (split hi/lo, swizzled)
    unsigned char* WH = smem + (c & 1) * 49152;
    unsigned char* WL = WH + 24576;
#pragma unroll
    for (int q = 0; q < 6; ++q) {
      int fid = q * 512 + t;
      int j = fid >> 4, c4 = fid & 15;
      int byte = j * 128 + ((((c4 >> 1) ^ (j & 7))) << 4) + ((c4 & 1) << 3);
      float4 v = wreg[q];
      unsigned short h0, h1, h2, h3, l0, l1, l2, l3;
      bf_split(v.x, h0, l0); bf_split(v.y, h1, l1);
      bf_split(v.z, h2, l2); bf_split(v.w, h3, l3);
      uint2 hv, lv;
      hv.x = (unsigned)h0 | ((unsigned)h1 << 16); hv.y = (unsigned)h2 | ((unsigned)h3 << 16);
      lv.x = (unsigned)l0 | ((unsigned)l1 << 16); lv.y = (unsigned)l2 | ((unsigned)l3 << 16);
      *(uint2*)(WH + byte) = hv;
      *(uint2*)(WL + byte) = lv;
    }
    // prefetch next chunk's W globals
    if (c < 11) {
#pragma unroll
      for (int q = 0; q < 6; ++q) {
        int fid = q * 512 + t;
        int j = fid >> 4, c4 = fid & 15;
        int sec = j >> 6, d = j & 63;
        wreg[q] = *(const float4*)(qkv_w + (size_t)(sec * DM + h * 64 + d) * DM + kc + 64 + c4 * 4);
      }
    }
    __syncthreads();
    // MFMA: 2 k-steps, split 3-pass
#pragma unroll
    for (int ks = 0; ks < 2; ++ks) {
      bf16x8 ah[2], al[2];
#pragma unroll
      for (int sm = 0; sm < 2; ++sm) {
        float xv[8];
        float4 v0 = xreg[(sm * 2 + ks) * 2 + 0], v1 = xreg[(sm * 2 + ks) * 2 + 1];
        xv[0] = v0.x; xv[1] = v0.y; xv[2] = v0.z; xv[3] = v0.w;
        xv[4] = v1.x; xv[5] = v1.y; xv[6] = v1.z; xv[7] = v1.w;
#pragma unroll
        for (int i = 0; i < 8; ++i) {
          unsigned short hi, lo;
          bf_split(xv[i], hi, lo);
          ah[sm][i] = (short)hi; al[sm][i] = (short)lo;
        }
      }
#pragma unroll
      for (int ns = 0; ns < 6; ++ns) {
        int j = wn * 96 + ns * 16 + ln;
        int sw = j * 128 + (((ks * 4 + g) ^ (j & 7)) << 4);
        bf16x8 bh = *(const bf16x8*)(WH + sw);
        bf16x8 bl = *(const bf16x8*)(WL + sw);
#pragma unroll
        for (int sm = 0; sm < 2; ++sm) {
          acc[sm][ns] = __builtin_amdgcn_mfma_f32_16x16x32_bf16(ah[sm], bh, acc[sm][ns], 0, 0, 0);
          acc[sm][ns] = __builtin_amdgcn_mfma_f32_16x16x32_bf16(ah[sm], bl, acc[sm][ns], 0, 0, 0);
          acc[sm][ns] = __builtin_amdgcn_mfma_f32_16x16x32_bf16(al[sm], bh, acc[sm][ns], 0, 0, 0);
        }
      }
    }
  }
  __syncthreads();   // all MFMA reads of Wbuf done before q/k/v overlay

  // ---- epilogue: bias, scatter q(split,scaled)/k(split)/v(transposed bf16)
#pragma unroll
  for (int sm = 0; sm < 2; ++sm)
#pragma unroll
    for (int ns = 0; ns < 6; ++ns) {
      int cc = wn * 96 + ns * 16 + ln;
      int sec = cc >> 6, dd = cc & 63;
      float bias = qkv_b[sec * DM + h * 64 + dd];
#pragma unroll
      for (int r = 0; r < 4; ++r) {
        int m = wm * 32 + sm * 16 + 4 * g + r;
        float val = acc[sm][ns][r] + bias;
        if (cc < 64) {
          val *= 0.125f;
          unsigned short hi, lo; bf_split(val, hi, lo);
          int byte = m * 128 + ((((dd >> 3) ^ (m & 7))) << 4) + ((dd & 7) << 1);
          *(unsigned short*)(smem + QH_OFF + byte) = hi;
          *(unsigned short*)(smem + QL_OFF + byte) = lo;
        } else if (cc < 128) {
          unsigned short hi, lo; bf_split(val, hi, lo);
          int byte = m * 128 + ((((dd >> 3) ^ (m & 7))) << 4) + ((dd & 7) << 1);
          *(unsigned short*)(smem + KH_OFF + byte) = hi;
          *(unsigned short*)(smem + KL_OFF + byte) = lo;
        } else {
          *(unsigned short*)(smem + VT_OFF + dd * 272 + m * 2) = bf_rne(val);
        }
      }
    }
  __syncthreads();

  // ---- Phase B: S = q @ k^T (split 3-pass), wave w owns rows w*16..+16
  const int mB = w * 16;
  f32x4 s2[8];
#pragma unroll
  for (int ns = 0; ns < 8; ++ns) s2[ns] = (f32x4){0.f, 0.f, 0.f, 0.f};
#pragma unroll
  for (int ks = 0; ks < 2; ++ks) {
    int arow = mB + ln;
    int abyte = arow * 128 + (((ks * 4 + g) ^ (arow & 7)) << 4);
    bf16x8 qh = *(const bf16x8*)(smem + QH_OFF + abyte);
    bf16x8 ql = *(const bf16x8*)(smem + QL_OFF + abyte);
#pragma unroll
    for (int ns = 0; ns < 8; ++ns) {
      int brow = ns * 16 + ln;
      int bbyte = brow * 128 + (((ks * 4 + g) ^ (brow & 7)) << 4);
      bf16x8 kh = *(const bf16x8*)(smem + KH_OFF + bbyte);
      bf16x8 kl = *(const bf16x8*)(smem + KL_OFF + bbyte);
      s2[ns] = __builtin_amdgcn_mfma_f32_16x16x32_bf16(qh, kh, s2[ns], 0, 0, 0);
      s2[ns] = __builtin_amdgcn_mfma_f32_16x16x32_bf16(qh, kl, s2[ns], 0, 0, 0);
      s2[ns] = __builtin_amdgcn_mfma_f32_16x16x32_bf16(ql, kh, s2[ns], 0, 0, 0);
    }
  }
  __syncthreads();   // q/k dead; P may overlay

  // ---- Phase C: softmax -> prune -> mask/eb -> softmax -> P (bf16)
  const float* mk = mask + (size_t)(bn & 127) * (WT * WT);
  const float* eb = edge_bias + (size_t)h * (WT * WT);
#pragma unroll
  for (int r = 0; r < 4; ++r) {
    int m = mB + 4 * g + r;
    float sv[8];
#pragma unroll
    for (int ns = 0; ns < 8; ++ns) sv[ns] = s2[ns][r];
    float m1 = sv[0];
#pragma unroll
    for (int ns = 1; ns < 8; ++ns) m1 = fmaxf(m1, sv[ns]);
#pragma unroll
    for (int off = 1; off < 16; off <<= 1) m1 = fmaxf(m1, __shfl_xor(m1, off, 64));
    float e[8], sum1 = 0.f;
#pragma unroll
    for (int ns = 0; ns < 8; ++ns) { e[ns] = __expf(sv[ns] - m1); sum1 += e[ns]; }
#pragma unroll
    for (int off = 1; off < 16; off <<= 1) sum1 += __shfl_xor(sum1, off, 64);
    float thr = 0.5f * sum1;
    float tv[8];
#pragma unroll
    for (int ns = 0; ns < 8; ++ns) {
      int col = ns * 16 + ln;
      float mkv = mk[m * WT + col];
      float ebv = eb[m * WT + col];
      float keep = (e[ns] > thr) ? 0.f : 1.f;
      float val = sv[ns] * keep * mkv * ebv;
      tv[ns] = (val == 0.f) ? -10000.f : val;
    }
    float m2 = tv[0];
#pragma unroll
    for (int ns = 1; ns < 8; ++ns) m2 = fmaxf(m2, tv[ns]);
#pragma unroll
    for (int off = 1; off < 16; off <<= 1) m2 = fmaxf(m2, __shfl_xor(m2, off, 64));
    float e2[8], sum2 = 0.f;
#pragma unroll
    for (int ns = 0; ns < 8; ++ns) { e2[ns] = __expf(tv[ns] - m2); sum2 += e2[ns]; }
#pragma unroll
    for (int off = 1; off < 16; off <<= 1) sum2 += __shfl_xor(sum2, off, 64);
    float inv = 1.f / sum2;
#pragma unroll
    for (int ns = 0; ns < 8; ++ns)
      *(unsigned short*)(smem + P_OFF + m * 272 + (ns * 16 + ln) * 2) = bf_rne(e2[ns] * inv);
  }
  __syncthreads();

  // ---- Phase D: out = P @ v  (plain bf16)
  f32x4 o4[4];
#pragma unroll
  for (int ns = 0; ns < 4; ++ns) o4[ns] = (f32x4){0.f, 0.f, 0.f, 0.f};
#pragma unroll
  for (int ks = 0; ks < 4; ++ks) {
    bf16x8 pa = *(const bf16x8*)(smem + P_OFF + (mB + ln) * 272 + ks * 64 + g * 16);
#pragma unroll
    for (int ns = 0; ns < 4; ++ns) {
      bf16x8 vb = *(const bf16x8*)(smem + VT_OFF + (ns * 16 + ln) * 272 + ks * 64 + g * 16);
      o4[ns] = __builtin_amdgcn_mfma_f32_16x16x32_bf16(pa, vb, o4[ns], 0, 0, 0);
    }
  }
#pragma unroll
  for (int ns = 0; ns < 4; ++ns)
#pragma unroll
    for (int r = 0; r < 4; ++r)
      out[(size_t)bn * (WT * DM) + (size_t)(mB + 4 * g + r) * DM + h * 64 + ns * 16 + ln] = o4[ns][r];
}

// ---------------- proj kernel: in-place-safe 64-row blocks, bf16 MFMA ----------
// LDS: A bf16 [64][768] swz @0 (98304) ; W2 bf16 pack2 [384][128B] swz @98304 (49152)
#define PA_OFF 0
#define PW_OFF 98304
#define SM_PROJ 147456

__global__ __launch_bounds__(512, 2) void proj_kernel(
    const float* __restrict__ src, const float* __restrict__ pw,
    const float* __restrict__ pb, float* __restrict__ dst)
{
  __shared__ __align__(16) unsigned char smem[SM_PROJ];
  const int t = threadIdx.x;
  const int lane = t & 63;
  const int w = t >> 6;
  const int g = lane >> 4;
  const int ln = lane & 15;
  const int wm = w & 1;      // 2 m-strips of 16 rows each (rows wm*32 + sm*16 ..)
  const int wn = w >> 1;     // 0..3, each 12 n-strips (192 cols)

  const int orig = blockIdx.x;
  const int wg = (orig & 7) * 128 + (orig >> 3);   // 1024 blocks, XCD-contiguous
  const size_t row0 = (size_t)wg * 64;

  // stage this block's 64 rows as bf16 (swizzled)
#pragma unroll
  for (int q = 0; q < 24; ++q) {
    int fid = q * 512 + t;
    int row = fid / 192, c4 = fid % 192;
    float4 v = *(const float4*)(src + (row0 + row) * DM + c4 * 4);
    int slot = c4 >> 1;
    int byte = row * 1536 + (((slot & ~7) | ((slot & 7) ^ (row & 7))) << 4) + ((c4 & 1) << 3);
    uint2 hv;
    hv.x = (unsigned)bf_rne(v.x) | ((unsigned)bf_rne(v.y) << 16);
    hv.y = (unsigned)bf_rne(v.z) | ((unsigned)bf_rne(v.w) << 16);
    *(uint2*)(smem + PA_OFF + byte) = hv;
  }

  f32x4 accp[2][12];
#pragma unroll
  for (int i = 0; i < 2; ++i)
#pragma unroll
    for (int j = 0; j < 12; ++j) accp[i][j] = (f32x4){0.f, 0.f, 0.f, 0.f};

  for (int c = 0; c < 24; ++c) {
    const int kc = c * 32;
    __syncthreads();   // prev MFMA reads done (also covers A staging at c=0)
    // stage W chunk [768 n][32 k] -> pack2 rows
#pragma unroll
    for (int q = 0; q < 12; ++q) {
      int fid = q * 512 + t;
      int n = fid >> 3, c4 = fid & 7;
      float4 v = *(const float4*)(pw + (size_t)n * DM + kc + c4 * 4);
      int slot = (n & 1) * 4 + (c4 >> 1);
      int byte = (n >> 1) * 128 + ((slot ^ ((n >> 1) & 7)) << 4) + ((c4 & 1) << 3);
      uint2 hv;
      hv.x = (unsigned)bf_rne(v.x) | ((unsigned)bf_rne(v.y) << 16);
      hv.y = (unsigned)bf_rne(v.z) | ((unsigned)bf_rne(v.w) << 16);
      *(uint2*)(smem + PW_OFF + byte) = hv;
    }
    __syncthreads();
    // MFMA: one 32-k step
    bf16x8 af[2];
#pragma unroll
    for (int sm = 0; sm < 2; ++sm) {
      int row = wm * 32 + sm * 16 + ln;
      int slot = (kc >> 3) + g;
      int byte = row * 1536 + (((slot & ~7) | ((slot & 7) ^ (row & 7))) << 4);
      af[sm] = *(const bf16x8*)(smem + PA_OFF + byte);
    }
#pragma unroll
    for (int j = 0; j < 12; ++j) {
      int n = (wn * 12 + j) * 16 + ln;
      int slot = (n & 1) * 4 + g;
      bf16x8 bf_ = *(const bf16x8*)(smem + PW_OFF + (n >> 1) * 128 + ((slot ^ ((n >> 1) & 7)) << 4));
#pragma unroll
      for (int sm = 0; sm < 2; ++sm)
        accp[sm][j] = __builtin_amdgcn_mfma_f32_16x16x32_bf16(af[sm], bf_, accp[sm][j], 0, 0, 0);
    }
  }

  // epilogue: bias + store (only this block's own rows)
#pragma unroll
  for (int j = 0; j < 12; ++j) {
    int col = (wn * 12 + j) * 16 + ln;
    float pbv = pb[col];
#pragma unroll
    for (int sm = 0; sm < 2; ++sm)
#pragma unroll
      for (int r = 0; r < 4; ++r)
        dst[(row0 + wm * 32 + sm * 16 + 4 * g + r) * DM + col] = accp[sm][j][r] + pbv;
  }
}

extern "C" void kernel_launch(void* const* d_in, const int* in_sizes, int n_in,
                              void* d_out, int out_size, void* d_ws, size_t ws_size,
                              hipStream_t stream) {
  const float* x         = (const float*)d_in[0];
  const float* qkv_w     = (const float*)d_in[1];
  const float* qkv_b     = (const float*)d_in[2];
  const float* proj_w    = (const float*)d_in[3];
  const float* proj_b    = (const float*)d_in[4];
  const float* edge_bias = (const float*)d_in[5];
  const float* mask      = (const float*)d_in[6];
  float* out = (float*)d_out;

  attn_kernel<<<NW * NH, 512, 0, stream>>>(x, qkv_w, qkv_b, edge_bias, mask, out);
  proj_kernel<<<NW * WT / 64, 512, 0, stream>>>(out, proj_w, proj_b, out);
}

// Round 3
// 1093.829 us; speedup vs baseline: 6.7586x; 1.4386x over previous
//
#include <hip/hip_runtime.h>

#define NW 512
#define WT 128
#define DM 768
#define NH 12

typedef __attribute__((ext_vector_type(8))) short bf16x8;
typedef __attribute__((ext_vector_type(4))) float f32x4;
typedef __attribute__((ext_vector_type(4))) unsigned int u32x4;

#define WCHUNK 24576                    // one (head,chunk) W image: hi 12288 + lo 12288
#define WS_NEED ((size_t)NH * 24 * WCHUNK)   // 7,077,888 bytes

__device__ __forceinline__ unsigned short bf_rne(float v) {
  unsigned u = __float_as_uint(v);
  unsigned r = u + 0x7fffu + ((u >> 16) & 1u);
  return (unsigned short)(r >> 16);
}
__device__ __forceinline__ void bf_split(float v, unsigned short& hi, unsigned short& lo) {
  hi = bf_rne(v);
  float hf = __uint_as_float(((unsigned)hi) << 16);
  lo = bf_rne(v - hf);
}

// packed RNE f32->bf16 pair: lo16 = bf16(a), hi16 = bf16(b)
__device__ __forceinline__ unsigned cvt_pk_bf16(float a, float b) {
  unsigned r;
  asm("v_cvt_pk_bf16_f32 %0, %1, %2" : "=v"(r) : "v"(a), "v"(b));
  return r;
}

// split 8 floats into 2-term bf16 (RNE hi, RNE lo) via cvt_pk: ~3 VALU/elem
__device__ __forceinline__ void split8(float4 v0, float4 v1, bf16x8& hi, bf16x8& lo) {
  float f[8] = {v0.x, v0.y, v0.z, v0.w, v1.x, v1.y, v1.z, v1.w};
  u32x4 hu, lu;
#pragma unroll
  for (int i = 0; i < 4; ++i) {
    float e0 = f[2 * i], e1 = f[2 * i + 1];
    unsigned hp = cvt_pk_bf16(e0, e1);
    float h0 = __uint_as_float(hp << 16);
    float h1 = __uint_as_float(hp & 0xffff0000u);
    lu[i] = cvt_pk_bf16(e0 - h0, e1 - h1);
    hu[i] = hp;
  }
  hi = __builtin_bit_cast(bf16x8, hu);
  lo = __builtin_bit_cast(bf16x8, lu);
}

__device__ __forceinline__ void gl_lds16(const void* g, void* l) {
  __builtin_amdgcn_global_load_lds(
      (const __attribute__((address_space(1))) void*)g,
      (__attribute__((address_space(3))) void*)l, 16, 0, 0);
}

// ---------------- precompute: W split -> swizzled LDS images in ws ----------
// image (h,c): 192 rows x 32 k, hi@0 lo@12288; row j byte:
//   j*64 + (((c4>>1) ^ (j&3))<<4) + ((c4&1)<<3),  c4 = k_local/4
__global__ __launch_bounds__(256) void split_w_kernel(
    const float* __restrict__ qkv_w, unsigned char* __restrict__ wsW)
{
  int id = blockIdx.x * 256 + threadIdx.x;      // 442368 total
  int c4 = id & 7;
  int j  = (id >> 3) % 192;
  int hc = (id >> 3) / 192;                     // h*24 + c
  int c  = hc % 24;
  int h  = hc / 24;
  int sec = j >> 6, d = j & 63;
  const float* src = qkv_w + (size_t)(sec * DM + h * 64 + d) * DM + c * 32 + c4 * 4;
  float4 v = *(const float4*)src;
  unsigned short h0, h1, h2, h3, l0, l1, l2, l3;
  bf_split(v.x, h0, l0); bf_split(v.y, h1, l1);
  bf_split(v.z, h2, l2); bf_split(v.w, h3, l3);
  uint2 hv, lv;
  hv.x = (unsigned)h0 | ((unsigned)h1 << 16); hv.y = (unsigned)h2 | ((unsigned)h3 << 16);
  lv.x = (unsigned)l0 | ((unsigned)l1 << 16); lv.y = (unsigned)l2 | ((unsigned)l3 << 16);
  int byte = j * 64 + (((c4 >> 1) ^ (j & 3)) << 4) + ((c4 & 1) << 3);
  unsigned char* base = wsW + (size_t)hc * WCHUNK;
  *(uint2*)(base + byte) = hv;
  *(uint2*)(base + 12288 + byte) = lv;
}

// ---------------- attn (PRE path) LDS layout (bytes) ----------------
// Phase A: W dbuf 2 x 24576 @0
// Post-A : QH@0 QL@16384 KH@32768 KL@49152 (each [128]x128B swz)
//          VT@65536: [64 d]x256B, slot swz = (tok>>3) ^ (d&15)
//          P @0: [128]x272B bf16 (overlays QH/QL + 2KB of KH)
#define QH_OFF 0
#define QL_OFF 16384
#define KH_OFF 32768
#define KL_OFF 49152
#define VT_OFF 65536
#define P_OFF  0

__global__ __launch_bounds__(512, 4) void attn_kernel_pre(
    const float* __restrict__ x, const unsigned char* __restrict__ wimg,
    const float* __restrict__ qkv_b, const float* __restrict__ edge_bias,
    const float* __restrict__ mask, float* __restrict__ out)
{
  __shared__ __align__(16) unsigned char smem[81920];
  const int t = threadIdx.x;
  const int lane = t & 63;
  const int w = t >> 6;          // 0..7
  const int g = lane >> 4;       // 0..3
  const int ln = lane & 15;      // 0..15
  const int wm = w & 3;          // m-block (32 rows)
  const int wn = w >> 2;         // strip parity

  const int orig = blockIdx.x;
  const int wg = (orig & 7) * 768 + (orig >> 3);   // XCD-contiguous, bijective
  const int h = wg % 12;
  const int bn = wg / 12;

  const float* xw = x + (size_t)bn * (WT * DM);
  const unsigned char* whead = wimg + (size_t)h * (24 * WCHUNK);

  f32x4 acc[2][6];
#pragma unroll
  for (int i = 0; i < 2; ++i)
#pragma unroll
    for (int j = 0; j < 6; ++j) acc[i][j] = (f32x4){0.f, 0.f, 0.f, 0.f};

  const float* xp0 = xw + (size_t)(wm * 32 + ln) * DM + g * 8;
  const float* xp1 = xp0 + 16 * DM;

  // prologue: stage W chunk 0 into buf0
  {
    const unsigned char* src = whead + t * 16;
    gl_lds16(src,         smem + t * 16);
    gl_lds16(src + 8192,  smem + t * 16 + 8192);
    gl_lds16(src + 16384, smem + t * 16 + 16384);
  }

  for (int c = 0; c < 24; ++c) {
    const int kc = c * 32;
    // x fragment loads + cheap split (chunk c)
    float4 a0 = *(const float4*)(xp0 + kc);
    float4 a1 = *(const float4*)(xp0 + kc + 4);
    float4 b0 = *(const float4*)(xp1 + kc);
    float4 b1 = *(const float4*)(xp1 + kc + 4);
    bf16x8 ah0, al0, ah1, al1;
    split8(a0, a1, ah0, al0);
    split8(b0, b1, ah1, al1);
    __syncthreads();             // W(c) resident; all waves past MFMA(c-1)
    if (c < 23) {                // prefetch W(c+1) into other buffer
      const unsigned char* src = whead + (size_t)(c + 1) * WCHUNK + t * 16;
      unsigned char* dst = smem + ((c + 1) & 1) * WCHUNK + t * 16;
      gl_lds16(src,         dst);
      gl_lds16(src + 8192,  dst + 8192);
      gl_lds16(src + 16384, dst + 16384);
    }
    const unsigned char* WH = smem + (c & 1) * WCHUNK;
    const unsigned char* WL = WH + 12288;
    // strips: cc = (ns*2+wn)*16+ln ; ns<4 -> q/k (3-pass), ns>=4 -> v (1-pass)
#pragma unroll
    for (int ns = 0; ns < 6; ++ns) {
      int j = (ns * 2 + wn) * 16 + ln;
      int sw = j * 64 + ((g ^ (j & 3)) << 4);
      bf16x8 bh = *(const bf16x8*)(WH + sw);
      acc[0][ns] = __builtin_amdgcn_mfma_f32_16x16x32_bf16(ah0, bh, acc[0][ns], 0, 0, 0);
      acc[1][ns] = __builtin_amdgcn_mfma_f32_16x16x32_bf16(ah1, bh, acc[1][ns], 0, 0, 0);
      if (ns < 4) {
        bf16x8 bl = *(const bf16x8*)(WL + sw);
        acc[0][ns] = __builtin_amdgcn_mfma_f32_16x16x32_bf16(ah0, bl, acc[0][ns], 0, 0, 0);
        acc[0][ns] = __builtin_amdgcn_mfma_f32_16x16x32_bf16(al0, bh, acc[0][ns], 0, 0, 0);
        acc[1][ns] = __builtin_amdgcn_mfma_f32_16x16x32_bf16(ah1, bl, acc[1][ns], 0, 0, 0);
        acc[1][ns] = __builtin_amdgcn_mfma_f32_16x16x32_bf16(al1, bh, acc[1][ns], 0, 0, 0);
      }
    }
  }
  __syncthreads();   // all MFMA reads of W bufs done before overlay

  // ---- epilogue: bias, scatter q(split,scaled)/k(split)/v(VT bf16)
#pragma unroll
  for (int ns = 0; ns < 6; ++ns) {
    int cc = (ns * 2 + wn) * 16 + ln;
    int sec = cc >> 6, dd = cc & 63;
    float bias = qkv_b[sec * DM + h * 64 + dd];
#pragma unroll
    for (int sm = 0; sm < 2; ++sm) {
#pragma unroll
      for (int r = 0; r < 4; ++r) {
        int m = wm * 32 + sm * 16 + 4 * g + r;
        float val = acc[sm][ns][r] + bias;
        if (cc < 64) {
          val *= 0.125f;
          unsigned short hi, lo; bf_split(val, hi, lo);
          int byte = m * 128 + (((dd >> 3) ^ (m & 7)) << 4) + ((dd & 7) << 1);
          *(unsigned short*)(smem + QH_OFF + byte) = hi;
          *(unsigned short*)(smem + QL_OFF + byte) = lo;
        } else if (cc < 128) {
          unsigned short hi, lo; bf_split(val, hi, lo);
          int byte = m * 128 + (((dd >> 3) ^ (m & 7)) << 4) + ((dd & 7) << 1);
          *(unsigned short*)(smem + KH_OFF + byte) = hi;
          *(unsigned short*)(smem + KL_OFF + byte) = lo;
        } else {
          int byte = dd * 256 + ((((m >> 3) ^ (dd & 15))) << 4) + ((m & 7) << 1);
          *(unsigned short*)(smem + VT_OFF + byte) = bf_rne(val);
        }
      }
    }
  }
  __syncthreads();

  // ---- Phase B: S = q @ k^T (split 3-pass), wave w owns rows w*16..+16
  const int mB = w * 16;
  f32x4 s2[8];
#pragma unroll
  for (int ns = 0; ns < 8; ++ns) s2[ns] = (f32x4){0.f, 0.f, 0.f, 0.f};
#pragma unroll
  for (int ks = 0; ks < 2; ++ks) {
    int arow = mB + ln;
    int abyte = arow * 128 + (((ks * 4 + g) ^ (arow & 7)) << 4);
    bf16x8 qh = *(const bf16x8*)(smem + QH_OFF + abyte);
    bf16x8 ql = *(const bf16x8*)(smem + QL_OFF + abyte);
#pragma unroll
    for (int ns = 0; ns < 8; ++ns) {
      int brow = ns * 16 + ln;
      int bbyte = brow * 128 + (((ks * 4 + g) ^ (brow & 7)) << 4);
      bf16x8 kh = *(const bf16x8*)(smem + KH_OFF + bbyte);
      bf16x8 kl = *(const bf16x8*)(smem + KL_OFF + bbyte);
      s2[ns] = __builtin_amdgcn_mfma_f32_16x16x32_bf16(qh, kh, s2[ns], 0, 0, 0);
      s2[ns] = __builtin_amdgcn_mfma_f32_16x16x32_bf16(qh, kl, s2[ns], 0, 0, 0);
      s2[ns] = __builtin_amdgcn_mfma_f32_16x16x32_bf16(ql, kh, s2[ns], 0, 0, 0);
    }
  }
  __syncthreads();   // q/k dead; P may overlay

  // ---- Phase C: softmax -> prune -> mask/eb -> softmax -> P (bf16)
  const float* mk = mask + (size_t)(bn & 127) * (WT * WT);
  const float* eb = edge_bias + (size_t)h * (WT * WT);
#pragma unroll
  for (int r = 0; r < 4; ++r) {
    int m = mB + 4 * g + r;
    float sv[8];
#pragma unroll
    for (int ns = 0; ns < 8; ++ns) sv[ns] = s2[ns][r];
    float m1 = sv[0];
#pragma unroll
    for (int ns = 1; ns < 8; ++ns) m1 = fmaxf(m1, sv[ns]);
#pragma unroll
    for (int off = 1; off < 16; off <<= 1) m1 = fmaxf(m1, __shfl_xor(m1, off, 64));
    float e[8], sum1 = 0.f;
#pragma unroll
    for (int ns = 0; ns < 8; ++ns) { e[ns] = __expf(sv[ns] - m1); sum1 += e[ns]; }
#pragma unroll
    for (int off = 1; off < 16; off <<= 1) sum1 += __shfl_xor(sum1, off, 64);
    float thr = 0.5f * sum1;
    float tv[8];
#pragma unroll
    for (int ns = 0; ns < 8; ++ns) {
      int col = ns * 16 + ln;
      float mkv = mk[m * WT + col];
      float ebv = eb[m * WT + col];
      float keep = (e[ns] > thr) ? 0.f : 1.f;
      float val = sv[ns] * keep * mkv * ebv;
      tv[ns] = (val == 0.f) ? -10000.f : val;
    }
    float m2 = tv[0];
#pragma unroll
    for (int ns = 1; ns < 8; ++ns) m2 = fmaxf(m2, tv[ns]);
#pragma unroll
    for (int off = 1; off < 16; off <<= 1) m2 = fmaxf(m2, __shfl_xor(m2, off, 64));
    float e2[8], sum2 = 0.f;
#pragma unroll
    for (int ns = 0; ns < 8; ++ns) { e2[ns] = __expf(tv[ns] - m2); sum2 += e2[ns]; }
#pragma unroll
    for (int off = 1; off < 16; off <<= 1) sum2 += __shfl_xor(sum2, off, 64);
    float inv = 1.f / sum2;
#pragma unroll
    for (int ns = 0; ns < 8; ++ns)
      *(unsigned short*)(smem + P_OFF + m * 272 + (ns * 16 + ln) * 2) = bf_rne(e2[ns] * inv);
  }
  __syncthreads();

  // ---- Phase D: out = P @ v  (plain bf16)
  f32x4 o4[4];
#pragma unroll
  for (int ns = 0; ns < 4; ++ns) o4[ns] = (f32x4){0.f, 0.f, 0.f, 0.f};
#pragma unroll
  for (int ks = 0; ks < 4; ++ks) {
    bf16x8 pa = *(const bf16x8*)(smem + P_OFF + (mB + ln) * 272 + ks * 64 + g * 16);
#pragma unroll
    for (int ns = 0; ns < 4; ++ns) {
      int d = ns * 16 + ln;
      bf16x8 vb = *(const bf16x8*)(smem + VT_OFF + d * 256 + (((ks * 4 + g) ^ (d & 15)) << 4));
      o4[ns] = __builtin_amdgcn_mfma_f32_16x16x32_bf16(pa, vb, o4[ns], 0, 0, 0);
    }
  }
#pragma unroll
  for (int ns = 0; ns < 4; ++ns)
#pragma unroll
    for (int r = 0; r < 4; ++r)
      out[(size_t)bn * (WT * DM) + (size_t)(mB + 4 * g + r) * DM + h * 64 + ns * 16 + ln] = o4[ns][r];
}

// ---------------- attn fallback (round-1 verified): used if ws too small ------
__global__ __launch_bounds__(512, 2) void attn_kernel_fb(
    const float* __restrict__ x, const float* __restrict__ qkv_w,
    const float* __restrict__ qkv_b, const float* __restrict__ edge_bias,
    const float* __restrict__ mask, float* __restrict__ out)
{
  __shared__ __align__(16) unsigned char smem[98304];
  const int t = threadIdx.x;
  const int lane = t & 63;
  const int w = t >> 6;
  const int g = lane >> 4;
  const int ln = lane & 15;
  const int wm = w & 3;
  const int wn = w >> 2;

  const int orig = blockIdx.x;
  const int wg = (orig & 7) * 768 + (orig >> 3);
  const int h = wg % 12;
  const int bn = wg / 12;

  const float* xw = x + (size_t)bn * (WT * DM);

  f32x4 acc[2][6];
#pragma unroll
  for (int i = 0; i < 2; ++i)
#pragma unroll
    for (int j = 0; j < 6; ++j) acc[i][j] = (f32x4){0.f, 0.f, 0.f, 0.f};

  float4 wreg[6], xreg[8];
#pragma unroll
  for (int q = 0; q < 6; ++q) {
    int fid = q * 512 + t;
    int j = fid >> 4, c4 = fid & 15;
    int sec = j >> 6, d = j & 63;
    wreg[q] = *(const float4*)(qkv_w + (size_t)(sec * DM + h * 64 + d) * DM + c4 * 4);
  }

  for (int c = 0; c < 12; ++c) {
    const int kc = c * 64;
#pragma unroll
    for (int sm = 0; sm < 2; ++sm)
#pragma unroll
      for (int ks = 0; ks < 2; ++ks) {
        int row = wm * 32 + sm * 16 + ln;
        const float* p = xw + (size_t)row * DM + kc + ks * 32 + g * 8;
        xreg[(sm * 2 + ks) * 2 + 0] = *(const float4*)p;
        xreg[(sm * 2 + ks) * 2 + 1] = *(const float4*)(p + 4);
      }
    unsigned char* WH = smem + (c & 1) * 49152;
    unsigned char* WL = WH + 24576;
#pragma unroll
    for (int q = 0; q < 6; ++q) {
      int fid = q * 512 + t;
      int j = fid >> 4, c4 = fid & 15;
      int byte = j * 128 + ((((c4 >> 1) ^ (j & 7))) << 4) + ((c4 & 1) << 3);
      float4 v = wreg[q];
      unsigned short h0, h1, h2, h3, l0, l1, l2, l3;
      bf_split(v.x, h0, l0); bf_split(v.y, h1, l1);
      bf_split(v.z, h2, l2); bf_split(v.w, h3, l3);
      uint2 hv, lv;
      hv.x = (unsigned)h0 | ((unsigned)h1 << 16); hv.y = (unsigned)h2 | ((unsigned)h3 << 16);
      lv.x = (unsigned)l0 | ((unsigned)l1 << 16); lv.y = (unsigned)l2 | ((unsigned)l3 << 16);
      *(uint2*)(WH + byte) = hv;
      *(uint2*)(WL + byte) = lv;
    }
    if (c < 11) {
#pragma unroll
      for (int q = 0; q < 6; ++q) {
        int fid = q * 512 + t;
        int j = fid >> 4, c4 = fid & 15;
        int sec = j >> 6, d = j & 63;
        wreg[q] = *(const float4*)(qkv_w + (size_t)(sec * DM + h * 64 + d) * DM + kc + 64 + c4 * 4);
      }
    }
    __syncthreads();
#pragma unroll
    for (int ks = 0; ks < 2; ++ks) {
      bf16x8 ah[2], al[2];
#pragma unroll
      for (int sm = 0; sm < 2; ++sm)
        split8(xreg[(sm * 2 + ks) * 2 + 0], xreg[(sm * 2 + ks) * 2 + 1], ah[sm], al[sm]);
#pragma unroll
      for (int ns = 0; ns < 6; ++ns) {
        int j = wn * 96 + ns * 16 + ln;
        int sw = j * 128 + (((ks * 4 + g) ^ (j & 7)) << 4);
        bf16x8 bh = *(const bf16x8*)(WH + sw);
        bf16x8 bl = *(const bf16x8*)(WL + sw);
#pragma unroll
        for (int sm = 0; sm < 2; ++sm) {
          acc[sm][ns] = __builtin_amdgcn_mfma_f32_16x16x32_bf16(ah[sm], bh, acc[sm][ns], 0, 0, 0);
          acc[sm][ns] = __builtin_amdgcn_mfma_f32_16x16x32_bf16(ah[sm], bl, acc[sm][ns], 0, 0, 0);
          acc[sm][ns] = __builtin_amdgcn_mfma_f32_16x16x32_bf16(al[sm], bh, acc[sm][ns], 0, 0, 0);
        }
      }
    }
  }
  __syncthreads();

#pragma unroll
  for (int sm = 0; sm < 2; ++sm)
#pragma unroll
    for (int ns = 0; ns < 6; ++ns) {
      int cc = wn * 96 + ns * 16 + ln;
      int sec = cc >> 6, dd = cc & 63;
      float bias = qkv_b[sec * DM + h * 64 + dd];
#pragma unroll
      for (int r = 0; r < 4; ++r) {
        int m = wm * 32 + sm * 16 + 4 * g + r;
        float val = acc[sm][ns][r] + bias;
        if (cc < 64) {
          val *= 0.125f;
          unsigned short hi, lo; bf_split(val, hi, lo);
          int byte = m * 128 + ((((dd >> 3) ^ (m & 7))) << 4) + ((dd & 7) << 1);
          *(unsigned short*)(smem + QH_OFF + byte) = hi;
          *(unsigned short*)(smem + QL_OFF + byte) = lo;
        } else if (cc < 128) {
          unsigned short hi, lo; bf_split(val, hi, lo);
          int byte = m * 128 + ((((dd >> 3) ^ (m & 7))) << 4) + ((dd & 7) << 1);
          *(unsigned short*)(smem + KH_OFF + byte) = hi;
          *(unsigned short*)(smem + KL_OFF + byte) = lo;
        } else {
          *(unsigned short*)(smem + VT_OFF + dd * 272 + m * 2) = bf_rne(val);
        }
      }
    }
  __syncthreads();

  const int mB = w * 16;
  f32x4 s2[8];
#pragma unroll
  for (int ns = 0; ns < 8; ++ns) s2[ns] = (f32x4){0.f, 0.f, 0.f, 0.f};
#pragma unroll
  for (int ks = 0; ks < 2; ++ks) {
    int arow = mB + ln;
    int abyte = arow * 128 + (((ks * 4 + g) ^ (arow & 7)) << 4);
    bf16x8 qh = *(const bf16x8*)(smem + QH_OFF + abyte);
    bf16x8 ql = *(const bf16x8*)(smem + QL_OFF + abyte);
#pragma unroll
    for (int ns = 0; ns < 8; ++ns) {
      int brow = ns * 16 + ln;
      int bbyte = brow * 128 + (((ks * 4 + g) ^ (brow & 7)) << 4);
      bf16x8 kh = *(const bf16x8*)(smem + KH_OFF + bbyte);
      bf16x8 kl = *(const bf16x8*)(smem + KL_OFF + bbyte);
      s2[ns] = __builtin_amdgcn_mfma_f32_16x16x32_bf16(qh, kh, s2[ns], 0, 0, 0);
      s2[ns] = __builtin_amdgcn_mfma_f32_16x16x32_bf16(qh, kl, s2[ns], 0, 0, 0);
      s2[ns] = __builtin_amdgcn_mfma_f32_16x16x32_bf16(ql, kh, s2[ns], 0, 0, 0);
    }
  }
  __syncthreads();

  const float* mk = mask + (size_t)(bn & 127) * (WT * WT);
  const float* eb = edge_bias + (size_t)h * (WT * WT);
#pragma unroll
  for (int r = 0; r < 4; ++r) {
    int m = mB + 4 * g + r;
    float sv[8];
#pragma unroll
    for (int ns = 0; ns < 8; ++ns) sv[ns] = s2[ns][r];
    float m1 = sv[0];
#pragma unroll
    for (int ns = 1; ns < 8; ++ns) m1 = fmaxf(m1, sv[ns]);
#pragma unroll
    for (int off = 1; off < 16; off <<= 1) m1 = fmaxf(m1, __shfl_xor(m1, off, 64));
    float e[8], sum1 = 0.f;
#pragma unroll
    for (int ns = 0; ns < 8; ++ns) { e[ns] = __expf(sv[ns] - m1); sum1 += e[ns]; }
#pragma unroll
    for (int off = 1; off < 16; off <<= 1) sum1 += __shfl_xor(sum1, off, 64);
    float thr = 0.5f * sum1;
    float tv[8];
#pragma unroll
    for (int ns = 0; ns < 8; ++ns) {
      int col = ns * 16 + ln;
      float mkv = mk[m * WT + col];
      float ebv = eb[m * WT + col];
      float keep = (e[ns] > thr) ? 0.f : 1.f;
      float val = sv[ns] * keep * mkv * ebv;
      tv[ns] = (val == 0.f) ? -10000.f : val;
    }
    float m2 = tv[0];
#pragma unroll
    for (int ns = 1; ns < 8; ++ns) m2 = fmaxf(m2, tv[ns]);
#pragma unroll
    for (int off = 1; off < 16; off <<= 1) m2 = fmaxf(m2, __shfl_xor(m2, off, 64));
    float e2[8], sum2 = 0.f;
#pragma unroll
    for (int ns = 0; ns < 8; ++ns) { e2[ns] = __expf(tv[ns] - m2); sum2 += e2[ns]; }
#pragma unroll
    for (int off = 1; off < 16; off <<= 1) sum2 += __shfl_xor(sum2, off, 64);
    float inv = 1.f / sum2;
#pragma unroll
    for (int ns = 0; ns < 8; ++ns)
      *(unsigned short*)(smem + P_OFF + m * 272 + (ns * 16 + ln) * 2) = bf_rne(e2[ns] * inv);
  }
  __syncthreads();

  f32x4 o4[4];
#pragma unroll
  for (int ns = 0; ns < 4; ++ns) o4[ns] = (f32x4){0.f, 0.f, 0.f, 0.f};
#pragma unroll
  for (int ks = 0; ks < 4; ++ks) {
    bf16x8 pa = *(const bf16x8*)(smem + P_OFF + (mB + ln) * 272 + ks * 64 + g * 16);
#pragma unroll
    for (int ns = 0; ns < 4; ++ns) {
      bf16x8 vb = *(const bf16x8*)(smem + VT_OFF + (ns * 16 + ln) * 272 + ks * 64 + g * 16);
      o4[ns] = __builtin_amdgcn_mfma_f32_16x16x32_bf16(pa, vb, o4[ns], 0, 0, 0);
    }
  }
#pragma unroll
  for (int ns = 0; ns < 4; ++ns)
#pragma unroll
    for (int r = 0; r < 4; ++r)
      out[(size_t)bn * (WT * DM) + (size_t)(mB + 4 * g + r) * DM + h * 64 + ns * 16 + ln] = o4[ns][r];
}

// ---------------- proj kernel: in-place-safe 64-row blocks, bf16 MFMA ----------
#define PA_OFF 0
#define PW_OFF 98304

__global__ __launch_bounds__(512, 2) void proj_kernel(
    const float* __restrict__ src, const float* __restrict__ pw,
    const float* __restrict__ pb, float* __restrict__ dst)
{
  __shared__ __align__(16) unsigned char smem[147456];
  const int t = threadIdx.x;
  const int lane = t & 63;
  const int w = t >> 6;
  const int g = lane >> 4;
  const int ln = lane & 15;
  const int wm = w & 1;
  const int wn = w >> 1;

  const int orig = blockIdx.x;
  const int wg = (orig & 7) * 128 + (orig >> 3);
  const size_t row0 = (size_t)wg * 64;

#pragma unroll
  for (int q = 0; q < 24; ++q) {
    int fid = q * 512 + t;
    int row = fid / 192, c4 = fid % 192;
    float4 v = *(const float4*)(src + (row0 + row) * DM + c4 * 4);
    int slot = c4 >> 1;
    int byte = row * 1536 + (((slot & ~7) | ((slot & 7) ^ (row & 7))) << 4) + ((c4 & 1) << 3);
    uint2 hv;
    hv.x = (unsigned)bf_rne(v.x) | ((unsigned)bf_rne(v.y) << 16);
    hv.y = (unsigned)bf_rne(v.z) | ((unsigned)bf_rne(v.w) << 16);
    *(uint2*)(smem + PA_OFF + byte) = hv;
  }

  f32x4 accp[2][12];
#pragma unroll
  for (int i = 0; i < 2; ++i)
#pragma unroll
    for (int j = 0; j < 12; ++j) accp[i][j] = (f32x4){0.f, 0.f, 0.f, 0.f};

  for (int c = 0; c < 24; ++c) {
    const int kc = c * 32;
    __syncthreads();
#pragma unroll
    for (int q = 0; q < 12; ++q) {
      int fid = q * 512 + t;
      int n = fid >> 3, c4 = fid & 7;
      float4 v = *(const float4*)(pw + (size_t)n * DM + kc + c4 * 4);
      int slot = (n & 1) * 4 + (c4 >> 1);
      int byte = (n >> 1) * 128 + ((slot ^ ((n >> 1) & 7)) << 4) + ((c4 & 1) << 3);
      uint2 hv;
      hv.x = (unsigned)bf_rne(v.x) | ((unsigned)bf_rne(v.y) << 16);
      hv.y = (unsigned)bf_rne(v.z) | ((unsigned)bf_rne(v.w) << 16);
      *(uint2*)(smem + PW_OFF + byte) = hv;
    }
    __syncthreads();
    bf16x8 af[2];
#pragma unroll
    for (int sm = 0; sm < 2; ++sm) {
      int row = wm * 32 + sm * 16 + ln;
      int slot = (kc >> 3) + g;
      int byte = row * 1536 + (((slot & ~7) | ((slot & 7) ^ (row & 7))) << 4);
      af[sm] = *(const bf16x8*)(smem + PA_OFF + byte);
    }
#pragma unroll
    for (int j = 0; j < 12; ++j) {
      int n = (wn * 12 + j) * 16 + ln;
      int slot = (n & 1) * 4 + g;
      bf16x8 bf_ = *(const bf16x8*)(smem + PW_OFF + (n >> 1) * 128 + ((slot ^ ((n >> 1) & 7)) << 4));
#pragma unroll
      for (int sm = 0; sm < 2; ++sm)
        accp[sm][j] = __builtin_amdgcn_mfma_f32_16x16x32_bf16(af[sm], bf_, accp[sm][j], 0, 0, 0);
    }
  }

#pragma unroll
  for (int j = 0; j < 12; ++j) {
    int col = (wn * 12 + j) * 16 + ln;
    float pbv = pb[col];
#pragma unroll
    for (int sm = 0; sm < 2; ++sm)
#pragma unroll
      for (int r = 0; r < 4; ++r)
        dst[(row0 + wm * 32 + sm * 16 + 4 * g + r) * DM + col] = accp[sm][j][r] + pbv;
  }
}

extern "C" void kernel_launch(void* const* d_in, const int* in_sizes, int n_in,
                              void* d_out, int out_size, void* d_ws, size_t ws_size,
                              hipStream_t stream) {
  const float* x         = (const float*)d_in[0];
  const float* qkv_w     = (const float*)d_in[1];
  const float* qkv_b     = (const float*)d_in[2];
  const float* proj_w    = (const float*)d_in[3];
  const float* proj_b    = (const float*)d_in[4];
  const float* edge_bias = (const float*)d_in[5];
  const float* mask      = (const float*)d_in[6];
  float* out = (float*)d_out;

  if (ws_size >= WS_NEED && d_ws != nullptr) {
    split_w_kernel<<<1728, 256, 0, stream>>>(qkv_w, (unsigned char*)d_ws);
    attn_kernel_pre<<<NW * NH, 512, 0, stream>>>(x, (const unsigned char*)d_ws,
                                                 qkv_b, edge_bias, mask, out);
  } else {
    attn_kernel_fb<<<NW * NH, 512, 0, stream>>>(x, qkv_w, qkv_b, edge_bias, mask, out);
  }
  proj_kernel<<<NW * WT / 64, 512, 0, stream>>>(out, proj_w, proj_b, out);
}

// Round 4
// 981.095 us; speedup vs baseline: 7.5352x; 1.1149x over previous
//
#include <hip/hip_runtime.h>

#define NW 512
#define WT 128
#define DM 768
#define NH 12

typedef __attribute__((ext_vector_type(8))) short bf16x8;
typedef __attribute__((ext_vector_type(4))) float f32x4;
typedef __attribute__((ext_vector_type(4))) unsigned int u32x4;

#define WCHUNK 24576                          // one (head,chunk) attn W image: hi 12288 + lo 12288
#define WS_W1 ((size_t)NH * 24 * WCHUNK)      // 7,077,888 attn W images
#define PWCHUNK 49152                         // one proj W k32 chunk image
#define WS_W2 ((size_t)24 * PWCHUNK)          // 1,179,648 proj W image

__device__ __forceinline__ unsigned short bf_rne(float v) {
  unsigned u = __float_as_uint(v);
  unsigned r = u + 0x7fffu + ((u >> 16) & 1u);
  return (unsigned short)(r >> 16);
}
__device__ __forceinline__ void bf_split(float v, unsigned short& hi, unsigned short& lo) {
  hi = bf_rne(v);
  float hf = __uint_as_float(((unsigned)hi) << 16);
  lo = bf_rne(v - hf);
}

// packed RNE f32->bf16 pair: lo16 = bf16(a), hi16 = bf16(b)
__device__ __forceinline__ unsigned cvt_pk_bf16(float a, float b) {
  unsigned r;
  asm("v_cvt_pk_bf16_f32 %0, %1, %2" : "=v"(r) : "v"(a), "v"(b));
  return r;
}
__device__ __forceinline__ unsigned short bf_rne_fast(float v) {
  return (unsigned short)cvt_pk_bf16(v, v);
}
__device__ __forceinline__ void bf_split_fast(float v, unsigned short& hi, unsigned short& lo) {
  unsigned hp = cvt_pk_bf16(v, v);
  float hf = __uint_as_float(hp << 16);
  lo = (unsigned short)cvt_pk_bf16(v - hf, v - hf);
  hi = (unsigned short)hp;
}

// split 8 floats into 2-term bf16 (RNE hi, RNE lo) via cvt_pk
__device__ __forceinline__ void split8(float4 v0, float4 v1, bf16x8& hi, bf16x8& lo) {
  float f[8] = {v0.x, v0.y, v0.z, v0.w, v1.x, v1.y, v1.z, v1.w};
  u32x4 hu, lu;
#pragma unroll
  for (int i = 0; i < 4; ++i) {
    float e0 = f[2 * i], e1 = f[2 * i + 1];
    unsigned hp = cvt_pk_bf16(e0, e1);
    float h0 = __uint_as_float(hp << 16);
    float h1 = __uint_as_float(hp & 0xffff0000u);
    lu[i] = cvt_pk_bf16(e0 - h0, e1 - h1);
    hu[i] = hp;
  }
  hi = __builtin_bit_cast(bf16x8, hu);
  lo = __builtin_bit_cast(bf16x8, lu);
}

__device__ __forceinline__ void gl_lds16(const void* g, void* l) {
  __builtin_amdgcn_global_load_lds(
      (const __attribute__((address_space(1))) void*)g,
      (__attribute__((address_space(3))) void*)l, 16, 0, 0);
}

// image row byte layout (shared by attn W and proj W images):
//   byte(j, c4) = j*64 + (((c4>>1) ^ ((j>>1)&3))<<4) + ((c4&1)<<3)
// frag read (k-slice g): j*64 + ((g ^ ((j>>1)&3))<<4)  -> 2-way banks (free)

// ---------------- precompute: attn W split -> swizzled LDS images ----------
__global__ __launch_bounds__(256) void split_w_kernel(
    const float* __restrict__ qkv_w, unsigned char* __restrict__ wsW)
{
  int id = blockIdx.x * 256 + threadIdx.x;      // 442368 total
  int c4 = id & 7;
  int j  = (id >> 3) % 192;
  int hc = (id >> 3) / 192;                     // h*24 + c
  int c  = hc % 24;
  int h  = hc / 24;
  int sec = j >> 6, d = j & 63;
  const float* src = qkv_w + (size_t)(sec * DM + h * 64 + d) * DM + c * 32 + c4 * 4;
  float4 v = *(const float4*)src;
  unsigned short h0, h1, h2, h3, l0, l1, l2, l3;
  bf_split(v.x, h0, l0); bf_split(v.y, h1, l1);
  bf_split(v.z, h2, l2); bf_split(v.w, h3, l3);
  uint2 hv, lv;
  hv.x = (unsigned)h0 | ((unsigned)h1 << 16); hv.y = (unsigned)h2 | ((unsigned)h3 << 16);
  lv.x = (unsigned)l0 | ((unsigned)l1 << 16); lv.y = (unsigned)l2 | ((unsigned)l3 << 16);
  int byte = j * 64 + (((c4 >> 1) ^ ((j >> 1) & 3)) << 4) + ((c4 & 1) << 3);
  unsigned char* base = wsW + (size_t)hc * WCHUNK;
  *(uint2*)(base + byte) = hv;
  *(uint2*)(base + 12288 + byte) = lv;
}

// ---------------- precompute: proj W -> bf16 swizzled LDS image ------------
__global__ __launch_bounds__(256) void split_pw_kernel(
    const float* __restrict__ pw, unsigned char* __restrict__ wsP)
{
  int id = blockIdx.x * 256 + threadIdx.x;      // 147456 total
  int c4 = id & 7;
  int n  = (id >> 3) % 768;
  int c  = (id >> 3) / 768;
  float4 v = *(const float4*)(pw + (size_t)n * DM + c * 32 + c4 * 4);
  uint2 hv;
  hv.x = (unsigned)bf_rne(v.x) | ((unsigned)bf_rne(v.y) << 16);
  hv.y = (unsigned)bf_rne(v.z) | ((unsigned)bf_rne(v.w) << 16);
  int byte = n * 64 + (((c4 >> 1) ^ ((n >> 1) & 3)) << 4) + ((c4 & 1) << 3);
  *(uint2*)(wsP + (size_t)c * PWCHUNK + byte) = hv;
}

// ---------------- attn (PRE path) LDS layout (bytes) ----------------
// Phase A: W 3-buffer rotate @ {0, 24576, 49152}   (73728 used)
// Post-A : QH@0 QL@16384 KH@32768 KL@49152 (each [128]x128B swz)
//          VT@65536: [64 d]x256B
//          P @0: [128]x272B bf16 (overlays QH/QL + 2KB of KH)
#define QH_OFF 0
#define QL_OFF 16384
#define KH_OFF 32768
#define KL_OFF 49152
#define VT_OFF 65536
#define P_OFF  0

__global__ __launch_bounds__(512, 4) void attn_kernel_pre(
    const float* __restrict__ x, const unsigned char* __restrict__ wimg,
    const float* __restrict__ qkv_b, const float* __restrict__ edge_bias,
    const float* __restrict__ mask, float* __restrict__ out)
{
  __shared__ __align__(16) unsigned char smem[81920];
  const int t = threadIdx.x;
  const int lane = t & 63;
  const int w = t >> 6;          // 0..7
  const int g = lane >> 4;       // 0..3
  const int ln = lane & 15;      // 0..15
  const int wm = w & 3;          // m-block (32 rows)
  const int wn = w >> 2;         // strip parity

  const int orig = blockIdx.x;
  const int wg = (orig & 7) * 768 + (orig >> 3);   // XCD-contiguous, bijective
  const int h = wg % 12;
  const int bn = wg / 12;

  const float* xw = x + (size_t)bn * (WT * DM);
  const unsigned char* whead = wimg + (size_t)h * (24 * WCHUNK);

  f32x4 acc[2][6];
#pragma unroll
  for (int i = 0; i < 2; ++i)
#pragma unroll
    for (int j = 0; j < 6; ++j) acc[i][j] = (f32x4){0.f, 0.f, 0.f, 0.f};

  const float* xp0 = xw + (size_t)(wm * 32 + ln) * DM + g * 8;
  const float* xp1 = xp0 + 16 * DM;

  // prologue: stage W chunks 0,1 into bufs 0,1 (STAGE issued before x loads)
  {
    const unsigned char* s0 = whead + t * 16;
#pragma unroll
    for (int i = 0; i < 3; ++i) gl_lds16(s0 + i * 8192, smem + t * 16 + i * 8192);
    const unsigned char* s1 = whead + WCHUNK + t * 16;
#pragma unroll
    for (int i = 0; i < 3; ++i) gl_lds16(s1 + i * 8192, smem + WCHUNK + t * 16 + i * 8192);
  }
  __builtin_amdgcn_sched_barrier(0);
  float4 xc0 = *(const float4*)(xp0);
  float4 xc1 = *(const float4*)(xp0 + 4);
  float4 xc2 = *(const float4*)(xp1);
  float4 xc3 = *(const float4*)(xp1 + 4);

  for (int c = 0; c < 24; ++c) {
    const int kn = (c + 1) * 32;
    float4 xn0, xn1, xn2, xn3;
    if (c < 23) {
      xn0 = *(const float4*)(xp0 + kn);
      xn1 = *(const float4*)(xp0 + kn + 4);
      xn2 = *(const float4*)(xp1 + kn);
      xn3 = *(const float4*)(xp1 + kn + 4);
    }
    // split waits on x(c) -> FIFO retires W(c) DMA too (STAGE pinned earlier)
    bf16x8 ah0, al0, ah1, al1;
    split8(xc0, xc1, ah0, al0);
    split8(xc2, xc3, ah1, al1);
    __builtin_amdgcn_sched_barrier(0);
    __builtin_amdgcn_s_barrier();
    __builtin_amdgcn_sched_barrier(0);
    if (c < 22) {                 // prefetch W(c+2), 2 chunks deep
      const unsigned char* src = whead + (size_t)(c + 2) * WCHUNK + t * 16;
      unsigned char* dst = smem + ((c + 2) % 3) * WCHUNK + t * 16;
      gl_lds16(src, dst);
      gl_lds16(src + 8192, dst + 8192);
      gl_lds16(src + 16384, dst + 16384);
    }
    __builtin_amdgcn_sched_barrier(0);   // pin STAGE before later x-loads
    const unsigned char* WH = smem + (c % 3) * WCHUNK;
    const unsigned char* WL = WH + 12288;
    __builtin_amdgcn_s_setprio(1);
    // strips: cc = (ns*2+wn)*16+ln ; ns<4 -> q/k (3-pass), ns>=4 -> v (1-pass)
#pragma unroll
    for (int ns = 0; ns < 6; ++ns) {
      int j = (ns * 2 + wn) * 16 + ln;
      int sw = j * 64 + ((g ^ ((j >> 1) & 3)) << 4);
      bf16x8 bh = *(const bf16x8*)(WH + sw);
      acc[0][ns] = __builtin_amdgcn_mfma_f32_16x16x32_bf16(ah0, bh, acc[0][ns], 0, 0, 0);
      acc[1][ns] = __builtin_amdgcn_mfma_f32_16x16x32_bf16(ah1, bh, acc[1][ns], 0, 0, 0);
      if (ns < 4) {
        bf16x8 bl = *(const bf16x8*)(WL + sw);
        acc[0][ns] = __builtin_amdgcn_mfma_f32_16x16x32_bf16(ah0, bl, acc[0][ns], 0, 0, 0);
        acc[0][ns] = __builtin_amdgcn_mfma_f32_16x16x32_bf16(al0, bh, acc[0][ns], 0, 0, 0);
        acc[1][ns] = __builtin_amdgcn_mfma_f32_16x16x32_bf16(ah1, bl, acc[1][ns], 0, 0, 0);
        acc[1][ns] = __builtin_amdgcn_mfma_f32_16x16x32_bf16(al1, bh, acc[1][ns], 0, 0, 0);
      }
    }
    __builtin_amdgcn_s_setprio(0);
    xc0 = xn0; xc1 = xn1; xc2 = xn2; xc3 = xn3;
  }
  __syncthreads();   // full drain before overlaying W buffers

  // ---- epilogue: bias, scatter q(split,scaled)/k(split)/v(VT bf16)
#pragma unroll
  for (int ns = 0; ns < 6; ++ns) {
    int cc = (ns * 2 + wn) * 16 + ln;
    int sec = cc >> 6, dd = cc & 63;
    float bias = qkv_b[sec * DM + h * 64 + dd];
#pragma unroll
    for (int sm = 0; sm < 2; ++sm) {
#pragma unroll
      for (int r = 0; r < 4; ++r) {
        int m = wm * 32 + sm * 16 + 4 * g + r;
        float val = acc[sm][ns][r] + bias;
        if (cc < 64) {
          val *= 0.125f;
          unsigned short hi, lo; bf_split_fast(val, hi, lo);
          int byte = m * 128 + (((dd >> 3) ^ (m & 7)) << 4) + ((dd & 7) << 1);
          *(unsigned short*)(smem + QH_OFF + byte) = hi;
          *(unsigned short*)(smem + QL_OFF + byte) = lo;
        } else if (cc < 128) {
          unsigned short hi, lo; bf_split_fast(val, hi, lo);
          int byte = m * 128 + (((dd >> 3) ^ (m & 7)) << 4) + ((dd & 7) << 1);
          *(unsigned short*)(smem + KH_OFF + byte) = hi;
          *(unsigned short*)(smem + KL_OFF + byte) = lo;
        } else {
          int byte = dd * 256 + ((((m >> 3) ^ (dd & 15))) << 4) + ((m & 7) << 1);
          *(unsigned short*)(smem + VT_OFF + byte) = bf_rne_fast(val);
        }
      }
    }
  }
  __syncthreads();

  // ---- Phase B: S = q @ k^T (split 3-pass), wave w owns rows w*16..+16
  const int mB = w * 16;
  f32x4 s2[8];
#pragma unroll
  for (int ns = 0; ns < 8; ++ns) s2[ns] = (f32x4){0.f, 0.f, 0.f, 0.f};
#pragma unroll
  for (int ks = 0; ks < 2; ++ks) {
    int arow = mB + ln;
    int abyte = arow * 128 + (((ks * 4 + g) ^ (arow & 7)) << 4);
    bf16x8 qh = *(const bf16x8*)(smem + QH_OFF + abyte);
    bf16x8 ql = *(const bf16x8*)(smem + QL_OFF + abyte);
#pragma unroll
    for (int ns = 0; ns < 8; ++ns) {
      int brow = ns * 16 + ln;
      int bbyte = brow * 128 + (((ks * 4 + g) ^ (brow & 7)) << 4);
      bf16x8 kh = *(const bf16x8*)(smem + KH_OFF + bbyte);
      bf16x8 kl = *(const bf16x8*)(smem + KL_OFF + bbyte);
      s2[ns] = __builtin_amdgcn_mfma_f32_16x16x32_bf16(qh, kh, s2[ns], 0, 0, 0);
      s2[ns] = __builtin_amdgcn_mfma_f32_16x16x32_bf16(qh, kl, s2[ns], 0, 0, 0);
      s2[ns] = __builtin_amdgcn_mfma_f32_16x16x32_bf16(ql, kh, s2[ns], 0, 0, 0);
    }
  }
  __syncthreads();   // q/k dead; P may overlay

  // ---- Phase C: softmax -> prune -> mask/eb -> softmax -> P (bf16)
  const float* mk = mask + (size_t)(bn & 127) * (WT * WT);
  const float* eb = edge_bias + (size_t)h * (WT * WT);
#pragma unroll
  for (int r = 0; r < 4; ++r) {
    int m = mB + 4 * g + r;
    float sv[8];
#pragma unroll
    for (int ns = 0; ns < 8; ++ns) sv[ns] = s2[ns][r];
    float m1 = sv[0];
#pragma unroll
    for (int ns = 1; ns < 8; ++ns) m1 = fmaxf(m1, sv[ns]);
#pragma unroll
    for (int off = 1; off < 16; off <<= 1) m1 = fmaxf(m1, __shfl_xor(m1, off, 64));
    float e[8], sum1 = 0.f;
#pragma unroll
    for (int ns = 0; ns < 8; ++ns) { e[ns] = __expf(sv[ns] - m1); sum1 += e[ns]; }
#pragma unroll
    for (int off = 1; off < 16; off <<= 1) sum1 += __shfl_xor(sum1, off, 64);
    float thr = 0.5f * sum1;
    float tv[8];
#pragma unroll
    for (int ns = 0; ns < 8; ++ns) {
      int col = ns * 16 + ln;
      float mkv = mk[m * WT + col];
      float ebv = eb[m * WT + col];
      float keep = (e[ns] > thr) ? 0.f : 1.f;
      float val = sv[ns] * keep * mkv * ebv;
      tv[ns] = (val == 0.f) ? -10000.f : val;
    }
    float m2 = tv[0];
#pragma unroll
    for (int ns = 1; ns < 8; ++ns) m2 = fmaxf(m2, tv[ns]);
#pragma unroll
    for (int off = 1; off < 16; off <<= 1) m2 = fmaxf(m2, __shfl_xor(m2, off, 64));
    float e2[8], sum2 = 0.f;
#pragma unroll
    for (int ns = 0; ns < 8; ++ns) { e2[ns] = __expf(tv[ns] - m2); sum2 += e2[ns]; }
#pragma unroll
    for (int off = 1; off < 16; off <<= 1) sum2 += __shfl_xor(sum2, off, 64);
    float inv = 1.f / sum2;
#pragma unroll
    for (int ns = 0; ns < 8; ++ns)
      *(unsigned short*)(smem + P_OFF + m * 272 + (ns * 16 + ln) * 2) = bf_rne_fast(e2[ns] * inv);
  }
  __syncthreads();

  // ---- Phase D: out = P @ v  (plain bf16)
  f32x4 o4[4];
#pragma unroll
  for (int ns = 0; ns < 4; ++ns) o4[ns] = (f32x4){0.f, 0.f, 0.f, 0.f};
#pragma unroll
  for (int ks = 0; ks < 4; ++ks) {
    bf16x8 pa = *(const bf16x8*)(smem + P_OFF + (mB + ln) * 272 + ks * 64 + g * 16);
#pragma unroll
    for (int ns = 0; ns < 4; ++ns) {
      int d = ns * 16 + ln;
      bf16x8 vb = *(const bf16x8*)(smem + VT_OFF + d * 256 + (((ks * 4 + g) ^ (d & 15)) << 4));
      o4[ns] = __builtin_amdgcn_mfma_f32_16x16x32_bf16(pa, vb, o4[ns], 0, 0, 0);
    }
  }
#pragma unroll
  for (int ns = 0; ns < 4; ++ns)
#pragma unroll
    for (int r = 0; r < 4; ++r)
      out[(size_t)bn * (WT * DM) + (size_t)(mB + 4 * g + r) * DM + h * 64 + ns * 16 + ln] = o4[ns][r];
}

// ---------------- proj (PRE path): 32-row blocks, W image via gl_lds ----------
// LDS: A bf16 [32][768] swz @0 (49152) ; W dbuf 2 x 49152 @49152
__global__ __launch_bounds__(512) void proj_kernel_pre(
    const float* src, const unsigned char* __restrict__ wimg,
    const float* __restrict__ pb, float* dst)
{
  __shared__ __align__(16) unsigned char smem[147456];
  const int t = threadIdx.x;
  const int lane = t & 63;
  const int w = t >> 6;          // 0..7, n-range w*96
  const int g = lane >> 4;
  const int ln = lane & 15;

  const int orig = blockIdx.x;
  const int wg = (orig & 7) * 256 + (orig >> 3);   // 2048 blocks, XCD-contiguous
  const size_t row0 = (size_t)wg * 32;

  // stage own 32 rows as bf16 (swizzled) — before any block overwrites them
#pragma unroll
  for (int q = 0; q < 12; ++q) {
    int fid = q * 512 + t;               // 6144 float4s, 192 per row
    int row = fid / 192, c4 = fid % 192;
    float4 v = *(const float4*)(src + (row0 + row) * DM + c4 * 4);
    int slot = c4 >> 1;
    int byte = row * 1536 + (((slot & ~7) | ((slot & 7) ^ (row & 7))) << 4) + ((c4 & 1) << 3);
    uint2 hv;
    hv.x = cvt_pk_bf16(v.x, v.y);
    hv.y = cvt_pk_bf16(v.z, v.w);
    *(uint2*)(smem + byte) = hv;
  }
  // prologue: W chunk 0
  {
    const unsigned char* sW = wimg + t * 16;
    unsigned char* dW = smem + 49152 + t * 16;
#pragma unroll
    for (int i = 0; i < 6; ++i) gl_lds16(sW + i * 8192, dW + i * 8192);
  }
  __syncthreads();

  f32x4 acc[2][6];
#pragma unroll
  for (int i = 0; i < 2; ++i)
#pragma unroll
    for (int j = 0; j < 6; ++j) acc[i][j] = (f32x4){0.f, 0.f, 0.f, 0.f};

  for (int c = 0; c < 24; ++c) {
    if (c) __syncthreads();            // drains W(c) DMA (hidden under MFMA(c-1))
    if (c < 23) {                      // prefetch W(c+1) into other buffer
      const unsigned char* sW = wimg + (size_t)(c + 1) * PWCHUNK + t * 16;
      unsigned char* dW = smem + 49152 + ((c + 1) & 1) * PWCHUNK + t * 16;
#pragma unroll
      for (int i = 0; i < 6; ++i) gl_lds16(sW + i * 8192, dW + i * 8192);
    }
    const unsigned char* WB = smem + 49152 + (c & 1) * PWCHUNK;
    __builtin_amdgcn_s_setprio(1);
    bf16x8 af[2];
#pragma unroll
    for (int sm = 0; sm < 2; ++sm) {
      int row = sm * 16 + ln;
      int slot = c * 4 + g;
      int byte = row * 1536 + (((slot & ~7) | ((slot & 7) ^ (row & 7))) << 4);
      af[sm] = *(const bf16x8*)(smem + byte);
    }
#pragma unroll
    for (int j = 0; j < 6; ++j) {
      int n = w * 96 + j * 16 + ln;
      bf16x8 bfrag = *(const bf16x8*)(WB + n * 64 + ((g ^ ((n >> 1) & 3)) << 4));
      acc[0][j] = __builtin_amdgcn_mfma_f32_16x16x32_bf16(af[0], bfrag, acc[0][j], 0, 0, 0);
      acc[1][j] = __builtin_amdgcn_mfma_f32_16x16x32_bf16(af[1], bfrag, acc[1][j], 0, 0, 0);
    }
    __builtin_amdgcn_s_setprio(0);
  }

  // epilogue: bias + store (only this block's own rows)
#pragma unroll
  for (int j = 0; j < 6; ++j) {
    int col = w * 96 + j * 16 + ln;
    float pbv = pb[col];
#pragma unroll
    for (int sm = 0; sm < 2; ++sm)
#pragma unroll
      for (int r = 0; r < 4; ++r)
        dst[(row0 + sm * 16 + 4 * g + r) * DM + col] = acc[sm][j][r] + pbv;
  }
}

// ---------------- attn fallback (round-2 verified): used if ws too small ------
__global__ __launch_bounds__(512, 2) void attn_kernel_fb(
    const float* __restrict__ x, const float* __restrict__ qkv_w,
    const float* __restrict__ qkv_b, const float* __restrict__ edge_bias,
    const float* __restrict__ mask, float* __restrict__ out)
{
  __shared__ __align__(16) unsigned char smem[98304];
  const int t = threadIdx.x;
  const int lane = t & 63;
  const int w = t >> 6;
  const int g = lane >> 4;
  const int ln = lane & 15;
  const int wm = w & 3;
  const int wn = w >> 2;

  const int orig = blockIdx.x;
  const int wg = (orig & 7) * 768 + (orig >> 3);
  const int h = wg % 12;
  const int bn = wg / 12;

  const float* xw = x + (size_t)bn * (WT * DM);

  f32x4 acc[2][6];
#pragma unroll
  for (int i = 0; i < 2; ++i)
#pragma unroll
    for (int j = 0; j < 6; ++j) acc[i][j] = (f32x4){0.f, 0.f, 0.f, 0.f};

  float4 wreg[6], xreg[8];
#pragma unroll
  for (int q = 0; q < 6; ++q) {
    int fid = q * 512 + t;
    int j = fid >> 4, c4 = fid & 15;
    int sec = j >> 6, d = j & 63;
    wreg[q] = *(const float4*)(qkv_w + (size_t)(sec * DM + h * 64 + d) * DM + c4 * 4);
  }

  for (int c = 0; c < 12; ++c) {
    const int kc = c * 64;
#pragma unroll
    for (int sm = 0; sm < 2; ++sm)
#pragma unroll
      for (int ks = 0; ks < 2; ++ks) {
        int row = wm * 32 + sm * 16 + ln;
        const float* p = xw + (size_t)row * DM + kc + ks * 32 + g * 8;
        xreg[(sm * 2 + ks) * 2 + 0] = *(const float4*)p;
        xreg[(sm * 2 + ks) * 2 + 1] = *(const float4*)(p + 4);
      }
    unsigned char* WH = smem + (c & 1) * 49152;
    unsigned char* WL = WH + 24576;
#pragma unroll
    for (int q = 0; q < 6; ++q) {
      int fid = q * 512 + t;
      int j = fid >> 4, c4 = fid & 15;
      int byte = j * 128 + ((((c4 >> 1) ^ (j & 7))) << 4) + ((c4 & 1) << 3);
      float4 v = wreg[q];
      unsigned short h0, h1, h2, h3, l0, l1, l2, l3;
      bf_split(v.x, h0, l0); bf_split(v.y, h1, l1);
      bf_split(v.z, h2, l2); bf_split(v.w, h3, l3);
      uint2 hv, lv;
      hv.x = (unsigned)h0 | ((unsigned)h1 << 16); hv.y = (unsigned)h2 | ((unsigned)h3 << 16);
      lv.x = (unsigned)l0 | ((unsigned)l1 << 16); lv.y = (unsigned)l2 | ((unsigned)l3 << 16);
      *(uint2*)(WH + byte) = hv;
      *(uint2*)(WL + byte) = lv;
    }
    if (c < 11) {
#pragma unroll
      for (int q = 0; q < 6; ++q) {
        int fid = q * 512 + t;
        int j = fid >> 4, c4 = fid & 15;
        int sec = j >> 6, d = j & 63;
        wreg[q] = *(const float4*)(qkv_w + (size_t)(sec * DM + h * 64 + d) * DM + kc + 64 + c4 * 4);
      }
    }
    __syncthreads();
#pragma unroll
    for (int ks = 0; ks < 2; ++ks) {
      bf16x8 ah[2], al[2];
#pragma unroll
      for (int sm = 0; sm < 2; ++sm)
        split8(xreg[(sm * 2 + ks) * 2 + 0], xreg[(sm * 2 + ks) * 2 + 1], ah[sm], al[sm]);
#pragma unroll
      for (int ns = 0; ns < 6; ++ns) {
        int j = wn * 96 + ns * 16 + ln;
        int sw = j * 128 + (((ks * 4 + g) ^ (j & 7)) << 4);
        bf16x8 bh = *(const bf16x8*)(WH + sw);
        bf16x8 bl = *(const bf16x8*)(WL + sw);
#pragma unroll
        for (int sm = 0; sm < 2; ++sm) {
          acc[sm][ns] = __builtin_amdgcn_mfma_f32_16x16x32_bf16(ah[sm], bh, acc[sm][ns], 0, 0, 0);
          acc[sm][ns] = __builtin_amdgcn_mfma_f32_16x16x32_bf16(ah[sm], bl, acc[sm][ns], 0, 0, 0);
          acc[sm][ns] = __builtin_amdgcn_mfma_f32_16x16x32_bf16(al[sm], bh, acc[sm][ns], 0, 0, 0);
        }
      }
    }
  }
  __syncthreads();

#pragma unroll
  for (int sm = 0; sm < 2; ++sm)
#pragma unroll
    for (int ns = 0; ns < 6; ++ns) {
      int cc = wn * 96 + ns * 16 + ln;
      int sec = cc >> 6, dd = cc & 63;
      float bias = qkv_b[sec * DM + h * 64 + dd];
#pragma unroll
      for (int r = 0; r < 4; ++r) {
        int m = wm * 32 + sm * 16 + 4 * g + r;
        float val = acc[sm][ns][r] + bias;
        if (cc < 64) {
          val *= 0.125f;
          unsigned short hi, lo; bf_split(val, hi, lo);
          int byte = m * 128 + ((((dd >> 3) ^ (m & 7))) << 4) + ((dd & 7) << 1);
          *(unsigned short*)(smem + QH_OFF + byte) = hi;
          *(unsigned short*)(smem + QL_OFF + byte) = lo;
        } else if (cc < 128) {
          unsigned short hi, lo; bf_split(val, hi, lo);
          int byte = m * 128 + ((((dd >> 3) ^ (m & 7))) << 4) + ((dd & 7) << 1);
          *(unsigned short*)(smem + KH_OFF + byte) = hi;
          *(unsigned short*)(smem + KL_OFF + byte) = lo;
        } else {
          *(unsigned short*)(smem + VT_OFF + dd * 272 + m * 2) = bf_rne(val);
        }
      }
    }
  __syncthreads();

  const int mB = w * 16;
  f32x4 s2[8];
#pragma unroll
  for (int ns = 0; ns < 8; ++ns) s2[ns] = (f32x4){0.f, 0.f, 0.f, 0.f};
#pragma unroll
  for (int ks = 0; ks < 2; ++ks) {
    int arow = mB + ln;
    int abyte = arow * 128 + (((ks * 4 + g) ^ (arow & 7)) << 4);
    bf16x8 qh = *(const bf16x8*)(smem + QH_OFF + abyte);
    bf16x8 ql = *(const bf16x8*)(smem + QL_OFF + abyte);
#pragma unroll
    for (int ns = 0; ns < 8; ++ns) {
      int brow = ns * 16 + ln;
      int bbyte = brow * 128 + (((ks * 4 + g) ^ (brow & 7)) << 4);
      bf16x8 kh = *(const bf16x8*)(smem + KH_OFF + bbyte);
      bf16x8 kl = *(const bf16x8*)(smem + KL_OFF + bbyte);
      s2[ns] = __builtin_amdgcn_mfma_f32_16x16x32_bf16(qh, kh, s2[ns], 0, 0, 0);
      s2[ns] = __builtin_amdgcn_mfma_f32_16x16x32_bf16(qh, kl, s2[ns], 0, 0, 0);
      s2[ns] = __builtin_amdgcn_mfma_f32_16x16x32_bf16(ql, kh, s2[ns], 0, 0, 0);
    }
  }
  __syncthreads();

  const float* mk = mask + (size_t)(bn & 127) * (WT * WT);
  const float* eb = edge_bias + (size_t)h * (WT * WT);
#pragma unroll
  for (int r = 0; r < 4; ++r) {
    int m = mB + 4 * g + r;
    float sv[8];
#pragma unroll
    for (int ns = 0; ns < 8; ++ns) sv[ns] = s2[ns][r];
    float m1 = sv[0];
#pragma unroll
    for (int ns = 1; ns < 8; ++ns) m1 = fmaxf(m1, sv[ns]);
#pragma unroll
    for (int off = 1; off < 16; off <<= 1) m1 = fmaxf(m1, __shfl_xor(m1, off, 64));
    float e[8], sum1 = 0.f;
#pragma unroll
    for (int ns = 0; ns < 8; ++ns) { e[ns] = __expf(sv[ns] - m1); sum1 += e[ns]; }
#pragma unroll
    for (int off = 1; off < 16; off <<= 1) sum1 += __shfl_xor(sum1, off, 64);
    float thr = 0.5f * sum1;
    float tv[8];
#pragma unroll
    for (int ns = 0; ns < 8; ++ns) {
      int col = ns * 16 + ln;
      float mkv = mk[m * WT + col];
      float ebv = eb[m * WT + col];
      float keep = (e[ns] > thr) ? 0.f : 1.f;
      float val = sv[ns] * keep * mkv * ebv;
      tv[ns] = (val == 0.f) ? -10000.f : val;
    }
    float m2 = tv[0];
#pragma unroll
    for (int ns = 1; ns < 8; ++ns) m2 = fmaxf(m2, tv[ns]);
#pragma unroll
    for (int off = 1; off < 16; off <<= 1) m2 = fmaxf(m2, __shfl_xor(m2, off, 64));
    float e2[8], sum2 = 0.f;
#pragma unroll
    for (int ns = 0; ns < 8; ++ns) { e2[ns] = __expf(tv[ns] - m2); sum2 += e2[ns]; }
#pragma unroll
    for (int off = 1; off < 16; off <<= 1) sum2 += __shfl_xor(sum2, off, 64);
    float inv = 1.f / sum2;
#pragma unroll
    for (int ns = 0; ns < 8; ++ns)
      *(unsigned short*)(smem + P_OFF + m * 272 + (ns * 16 + ln) * 2) = bf_rne(e2[ns] * inv);
  }
  __syncthreads();

  f32x4 o4[4];
#pragma unroll
  for (int ns = 0; ns < 4; ++ns) o4[ns] = (f32x4){0.f, 0.f, 0.f, 0.f};
#pragma unroll
  for (int ks = 0; ks < 4; ++ks) {
    bf16x8 pa = *(const bf16x8*)(smem + P_OFF + (mB + ln) * 272 + ks * 64 + g * 16);
#pragma unroll
    for (int ns = 0; ns < 4; ++ns) {
      bf16x8 vb = *(const bf16x8*)(smem + VT_OFF + (ns * 16 + ln) * 272 + ks * 64 + g * 16);
      o4[ns] = __builtin_amdgcn_mfma_f32_16x16x32_bf16(pa, vb, o4[ns], 0, 0, 0);
    }
  }
#pragma unroll
  for (int ns = 0; ns < 4; ++ns)
#pragma unroll
    for (int r = 0; r < 4; ++r)
      out[(size_t)bn * (WT * DM) + (size_t)(mB + 4 * g + r) * DM + h * 64 + ns * 16 + ln] = o4[ns][r];
}

// ---------------- proj fallback: round-2/3 verified 64-row version ------------
#define PA_OFF 0
#define PW_OFF 98304

__global__ __launch_bounds__(512, 2) void proj_kernel_fb(
    const float* src, const float* __restrict__ pw,
    const float* __restrict__ pb, float* dst)
{
  __shared__ __align__(16) unsigned char smem[147456];
  const int t = threadIdx.x;
  const int lane = t & 63;
  const int w = t >> 6;
  const int g = lane >> 4;
  const int ln = lane & 15;
  const int wm = w & 1;
  const int wn = w >> 1;

  const int orig = blockIdx.x;
  const int wg = (orig & 7) * 128 + (orig >> 3);
  const size_t row0 = (size_t)wg * 64;

#pragma unroll
  for (int q = 0; q < 24; ++q) {
    int fid = q * 512 + t;
    int row = fid / 192, c4 = fid % 192;
    float4 v = *(const float4*)(src + (row0 + row) * DM + c4 * 4);
    int slot = c4 >> 1;
    int byte = row * 1536 + (((slot & ~7) | ((slot & 7) ^ (row & 7))) << 4) + ((c4 & 1) << 3);
    uint2 hv;
    hv.x = (unsigned)bf_rne(v.x) | ((unsigned)bf_rne(v.y) << 16);
    hv.y = (unsigned)bf_rne(v.z) | ((unsigned)bf_rne(v.w) << 16);
    *(uint2*)(smem + PA_OFF + byte) = hv;
  }

  f32x4 accp[2][12];
#pragma unroll
  for (int i = 0; i < 2; ++i)
#pragma unroll
    for (int j = 0; j < 12; ++j) accp[i][j] = (f32x4){0.f, 0.f, 0.f, 0.f};

  for (int c = 0; c < 24; ++c) {
    const int kc = c * 32;
    __syncthreads();
#pragma unroll
    for (int q = 0; q < 12; ++q) {
      int fid = q * 512 + t;
      int n = fid >> 3, c4 = fid & 7;
      float4 v = *(const float4*)(pw + (size_t)n * DM + kc + c4 * 4);
      int slot = (n & 1) * 4 + (c4 >> 1);
      int byte = (n >> 1) * 128 + ((slot ^ ((n >> 1) & 7)) << 4) + ((c4 & 1) << 3);
      uint2 hv;
      hv.x = (unsigned)bf_rne(v.x) | ((unsigned)bf_rne(v.y) << 16);
      hv.y = (unsigned)bf_rne(v.z) | ((unsigned)bf_rne(v.w) << 16);
      *(uint2*)(smem + PW_OFF + byte) = hv;
    }
    __syncthreads();
    bf16x8 af[2];
#pragma unroll
    for (int sm = 0; sm < 2; ++sm) {
      int row = wm * 32 + sm * 16 + ln;
      int slot = (kc >> 3) + g;
      int byte = row * 1536 + (((slot & ~7) | ((slot & 7) ^ (row & 7))) << 4);
      af[sm] = *(const bf16x8*)(smem + PA_OFF + byte);
    }
#pragma unroll
    for (int j = 0; j < 12; ++j) {
      int n = (wn * 12 + j) * 16 + ln;
      int slot = (n & 1) * 4 + g;
      bf16x8 bf_ = *(const bf16x8*)(smem + PW_OFF + (n >> 1) * 128 + ((slot ^ ((n >> 1) & 7)) << 4));
#pragma unroll
      for (int sm = 0; sm < 2; ++sm)
        accp[sm][j] = __builtin_amdgcn_mfma_f32_16x16x32_bf16(af[sm], bf_, accp[sm][j], 0, 0, 0);
    }
  }

#pragma unroll
  for (int j = 0; j < 12; ++j) {
    int col = (wn * 12 + j) * 16 + ln;
    float pbv = pb[col];
#pragma unroll
    for (int sm = 0; sm < 2; ++sm)
#pragma unroll
      for (int r = 0; r < 4; ++r)
        dst[(row0 + wm * 32 + sm * 16 + 4 * g + r) * DM + col] = accp[sm][j][r] + pbv;
  }
}

extern "C" void kernel_launch(void* const* d_in, const int* in_sizes, int n_in,
                              void* d_out, int out_size, void* d_ws, size_t ws_size,
                              hipStream_t stream) {
  const float* x         = (const float*)d_in[0];
  const float* qkv_w     = (const float*)d_in[1];
  const float* qkv_b     = (const float*)d_in[2];
  const float* proj_w    = (const float*)d_in[3];
  const float* proj_b    = (const float*)d_in[4];
  const float* edge_bias = (const float*)d_in[5];
  const float* mask      = (const float*)d_in[6];
  float* out = (float*)d_out;

  const bool p1 = (d_ws != nullptr) && (ws_size >= WS_W1);
  const bool p2 = (d_ws != nullptr) && (ws_size >= WS_W1 + WS_W2);
  unsigned char* wsW = (unsigned char*)d_ws;
  unsigned char* wsP = wsW + WS_W1;

  if (p1) {
    split_w_kernel<<<1728, 256, 0, stream>>>(qkv_w, wsW);
  }
  if (p2) {
    split_pw_kernel<<<576, 256, 0, stream>>>(proj_w, wsP);
  }
  if (p1) {
    attn_kernel_pre<<<NW * NH, 512, 0, stream>>>(x, wsW, qkv_b, edge_bias, mask, out);
  } else {
    attn_kernel_fb<<<NW * NH, 512, 0, stream>>>(x, qkv_w, qkv_b, edge_bias, mask, out);
  }
  if (p2) {
    proj_kernel_pre<<<2048, 512, 0, stream>>>(out, wsP, proj_b, out);
  } else {
    proj_kernel_fb<<<1024, 512, 0, stream>>>(out, proj_w, proj_b, out);
  }
}

// Round 5
// 828.140 us; speedup vs baseline: 8.9269x; 1.1847x over previous
//
#include <hip/hip_runtime.h>

#define NW 512
#define WT 128
#define DM 768
#define NH 12

typedef __attribute__((ext_vector_type(8))) short bf16x8;
typedef __attribute__((ext_vector_type(4))) float f32x4;
typedef __attribute__((ext_vector_type(4))) unsigned int u32x4;

#define WCHUNK 24576                          // one (head,chunk) attn W image: hi 12288 + lo 12288
#define WS_W1 ((size_t)NH * 24 * WCHUNK)      // 7,077,888 attn W images
#define PWCHUNK 49152                         // one proj W k32 chunk image
#define WS_W2 ((size_t)24 * PWCHUNK)          // 1,179,648 proj W image

__device__ __forceinline__ unsigned short bf_rne(float v) {
  unsigned u = __float_as_uint(v);
  unsigned r = u + 0x7fffu + ((u >> 16) & 1u);
  return (unsigned short)(r >> 16);
}
__device__ __forceinline__ void bf_split(float v, unsigned short& hi, unsigned short& lo) {
  hi = bf_rne(v);
  float hf = __uint_as_float(((unsigned)hi) << 16);
  lo = bf_rne(v - hf);
}

// packed RNE f32->bf16 pair: lo16 = bf16(a), hi16 = bf16(b)
__device__ __forceinline__ unsigned cvt_pk_bf16(float a, float b) {
  unsigned r;
  asm("v_cvt_pk_bf16_f32 %0, %1, %2" : "=v"(r) : "v"(a), "v"(b));
  return r;
}
__device__ __forceinline__ unsigned short bf_rne_fast(float v) {
  return (unsigned short)cvt_pk_bf16(v, v);
}
__device__ __forceinline__ void bf_split_fast(float v, unsigned short& hi, unsigned short& lo) {
  unsigned hp = cvt_pk_bf16(v, v);
  float hf = __uint_as_float(hp << 16);
  lo = (unsigned short)cvt_pk_bf16(v - hf, v - hf);
  hi = (unsigned short)hp;
}

// split 8 floats into 2-term bf16 (RNE hi, RNE lo) via cvt_pk
__device__ __forceinline__ void split8(float4 v0, float4 v1, bf16x8& hi, bf16x8& lo) {
  float f[8] = {v0.x, v0.y, v0.z, v0.w, v1.x, v1.y, v1.z, v1.w};
  u32x4 hu, lu;
#pragma unroll
  for (int i = 0; i < 4; ++i) {
    float e0 = f[2 * i], e1 = f[2 * i + 1];
    unsigned hp = cvt_pk_bf16(e0, e1);
    float h0 = __uint_as_float(hp << 16);
    float h1 = __uint_as_float(hp & 0xffff0000u);
    lu[i] = cvt_pk_bf16(e0 - h0, e1 - h1);
    hu[i] = hp;
  }
  hi = __builtin_bit_cast(bf16x8, hu);
  lo = __builtin_bit_cast(bf16x8, lu);
}

__device__ __forceinline__ void gl_lds16(const void* g, void* l) {
  __builtin_amdgcn_global_load_lds(
      (const __attribute__((address_space(1))) void*)g,
      (__attribute__((address_space(3))) void*)l, 16, 0, 0);
}

// image row byte layout (shared by attn W and proj W images):
//   byte(j, c4) = j*64 + (((c4>>1) ^ ((j>>1)&3))<<4) + ((c4&1)<<3)
// frag read (k-slice g): j*64 + ((g ^ ((j>>1)&3))<<4)  -> 2-way banks (free)

// ---------------- precompute: attn W split -> swizzled LDS images ----------
__global__ __launch_bounds__(256) void split_w_kernel(
    const float* __restrict__ qkv_w, unsigned char* __restrict__ wsW)
{
  int id = blockIdx.x * 256 + threadIdx.x;      // 442368 total
  int c4 = id & 7;
  int j  = (id >> 3) % 192;
  int hc = (id >> 3) / 192;                     // h*24 + c
  int c  = hc % 24;
  int h  = hc / 24;
  int sec = j >> 6, d = j & 63;
  const float* src = qkv_w + (size_t)(sec * DM + h * 64 + d) * DM + c * 32 + c4 * 4;
  float4 v = *(const float4*)src;
  unsigned short h0, h1, h2, h3, l0, l1, l2, l3;
  bf_split(v.x, h0, l0); bf_split(v.y, h1, l1);
  bf_split(v.z, h2, l2); bf_split(v.w, h3, l3);
  uint2 hv, lv;
  hv.x = (unsigned)h0 | ((unsigned)h1 << 16); hv.y = (unsigned)h2 | ((unsigned)h3 << 16);
  lv.x = (unsigned)l0 | ((unsigned)l1 << 16); lv.y = (unsigned)l2 | ((unsigned)l3 << 16);
  int byte = j * 64 + (((c4 >> 1) ^ ((j >> 1) & 3)) << 4) + ((c4 & 1) << 3);
  unsigned char* base = wsW + (size_t)hc * WCHUNK;
  *(uint2*)(base + byte) = hv;
  *(uint2*)(base + 12288 + byte) = lv;
}

// ---------------- precompute: proj W -> bf16 swizzled LDS image ------------
__global__ __launch_bounds__(256) void split_pw_kernel(
    const float* __restrict__ pw, unsigned char* __restrict__ wsP)
{
  int id = blockIdx.x * 256 + threadIdx.x;      // 147456 total
  int c4 = id & 7;
  int n  = (id >> 3) % 768;
  int c  = (id >> 3) / 768;
  float4 v = *(const float4*)(pw + (size_t)n * DM + c * 32 + c4 * 4);
  uint2 hv;
  hv.x = (unsigned)bf_rne(v.x) | ((unsigned)bf_rne(v.y) << 16);
  hv.y = (unsigned)bf_rne(v.z) | ((unsigned)bf_rne(v.w) << 16);
  int byte = n * 64 + (((c4 >> 1) ^ ((n >> 1) & 3)) << 4) + ((c4 & 1) << 3);
  *(uint2*)(wsP + (size_t)c * PWCHUNK + byte) = hv;
}

// ---------------- attn (PRE path) LDS layout (bytes) ----------------
// Phase A: W dbuf 2 x 24576 @0 ; EX dbuf 2 x 16384 @49152  (81920 total)
// Post-A : QH@0 QL@16384 KH@32768 KL@49152 (each [128]x128B swz)
//          VT@65536: [64 d]x256B
//          P @0: [128]x272B bf16 (overlays QH/QL + 2KB of KH)
#define QH_OFF 0
#define QL_OFF 16384
#define KH_OFF 32768
#define KL_OFF 49152
#define VT_OFF 65536
#define EX_OFF 49152
#define P_OFF  0

__global__ __launch_bounds__(512, 4) void attn_kernel_pre(
    const float* __restrict__ x, const unsigned char* __restrict__ wimg,
    const float* __restrict__ qkv_b, const float* __restrict__ edge_bias,
    const float* __restrict__ mask, float* __restrict__ out)
{
  __shared__ __align__(16) unsigned char smem[81920];
  const int t = threadIdx.x;
  const int lane = t & 63;
  const int w = t >> 6;          // 0..7
  const int g = lane >> 4;       // 0..3
  const int ln = lane & 15;      // 0..15
  const int wm = w & 3;          // m-block (32 rows)
  const int wn = w >> 2;         // strip parity / k-half for x staging

  const int orig = blockIdx.x;
  const int wg = (orig & 7) * 768 + (orig >> 3);   // XCD-contiguous, bijective
  const int h = wg % 12;
  const int bn = wg / 12;

  const float* xw = x + (size_t)bn * (WT * DM);
  const unsigned char* whead = wimg + (size_t)h * (24 * WCHUNK);

  f32x4 acc[2][6];
#pragma unroll
  for (int i = 0; i < 2; ++i)
#pragma unroll
    for (int j = 0; j < 6; ++j) acc[i][j] = (f32x4){0.f, 0.f, 0.f, 0.f};

  // x half-load: this wave stages rows wm*32+(lane&31), k-half wn*16+(lane>>5)*8
  const int exr = wm * 32 + (lane & 31);
  const int exs = wn * 2 + (lane >> 5);
  const float* xptr = xw + (size_t)exr * DM + wn * 16 + (lane >> 5) * 8;
  const int ex_w_hi = exr * 128 + ((exs ^ (exr & 7)) << 4);
  const int ex_w_lo = exr * 128 + (((exs + 4) ^ (exr & 7)) << 4);
  int ex_r_h[2], ex_r_l[2];
#pragma unroll
  for (int sm = 0; sm < 2; ++sm) {
    int rr = wm * 32 + sm * 16 + ln;
    ex_r_h[sm] = rr * 128 + ((g ^ (rr & 7)) << 4);
    ex_r_l[sm] = rr * 128 + (((g + 4) ^ (rr & 7)) << 4);
  }

  // prologue: stage W(0) into buf0, then load x(0)
  {
    const unsigned char* s0 = whead + t * 16;
#pragma unroll
    for (int i = 0; i < 3; ++i) gl_lds16(s0 + i * 8192, smem + t * 16 + i * 8192);
  }
  __builtin_amdgcn_sched_barrier(0);
  float4 xa = *(const float4*)xptr;
  float4 xb = *(const float4*)(xptr + 4);
  __builtin_amdgcn_sched_barrier(0);

  for (int c = 0; c < 24; ++c) {
    // (a) issue x(c+1) loads
    float4 na, nb;
    if (c < 23) {
      na = *(const float4*)(xptr + (c + 1) * 32);
      nb = *(const float4*)(xptr + (c + 1) * 32 + 4);
    }
    __builtin_amdgcn_sched_barrier(0);
    // (b) split x(c) (compiler waits x(c)) + exchange writes
    bf16x8 xh8, xl8;
    split8(xa, xb, xh8, xl8);
    unsigned char* exb = smem + EX_OFF + (c & 1) * 16384;
    *(bf16x8*)(exb + ex_w_hi) = xh8;
    *(bf16x8*)(exb + ex_w_lo) = xl8;
    __builtin_amdgcn_sched_barrier(0);
    // (c) retire own W(c) DMA (keep x(c+1) in flight), drain LDS writes, barrier
    if (c < 23) asm volatile("s_waitcnt vmcnt(2)" ::: "memory");
    else        asm volatile("s_waitcnt vmcnt(0)" ::: "memory");
    asm volatile("s_waitcnt lgkmcnt(0)" ::: "memory");
    __builtin_amdgcn_s_barrier();
    __builtin_amdgcn_sched_barrier(0);
    // (d) stage W(c+1) into other buffer
    if (c < 23) {
      const unsigned char* src = whead + (size_t)(c + 1) * WCHUNK + t * 16;
      unsigned char* dst = smem + ((c + 1) & 1) * WCHUNK + t * 16;
      gl_lds16(src, dst);
      gl_lds16(src + 8192, dst + 8192);
      gl_lds16(src + 16384, dst + 16384);
    }
    __builtin_amdgcn_sched_barrier(0);
    // (e) fragments + MFMA
    const unsigned char* WH = smem + (c & 1) * WCHUNK;
    const unsigned char* WL = WH + 12288;
    bf16x8 ah0 = *(const bf16x8*)(exb + ex_r_h[0]);
    bf16x8 al0 = *(const bf16x8*)(exb + ex_r_l[0]);
    bf16x8 ah1 = *(const bf16x8*)(exb + ex_r_h[1]);
    bf16x8 al1 = *(const bf16x8*)(exb + ex_r_l[1]);
    __builtin_amdgcn_s_setprio(1);
    // strips: cc = (ns*2+wn)*16+ln ; ns<4 -> q/k (3-pass), ns>=4 -> v (1-pass)
#pragma unroll
    for (int ns = 0; ns < 6; ++ns) {
      int j = (ns * 2 + wn) * 16 + ln;
      int sw = j * 64 + ((g ^ ((j >> 1) & 3)) << 4);
      bf16x8 bh = *(const bf16x8*)(WH + sw);
      acc[0][ns] = __builtin_amdgcn_mfma_f32_16x16x32_bf16(ah0, bh, acc[0][ns], 0, 0, 0);
      acc[1][ns] = __builtin_amdgcn_mfma_f32_16x16x32_bf16(ah1, bh, acc[1][ns], 0, 0, 0);
      if (ns < 4) {
        bf16x8 bl = *(const bf16x8*)(WL + sw);
        acc[0][ns] = __builtin_amdgcn_mfma_f32_16x16x32_bf16(ah0, bl, acc[0][ns], 0, 0, 0);
        acc[0][ns] = __builtin_amdgcn_mfma_f32_16x16x32_bf16(al0, bh, acc[0][ns], 0, 0, 0);
        acc[1][ns] = __builtin_amdgcn_mfma_f32_16x16x32_bf16(ah1, bl, acc[1][ns], 0, 0, 0);
        acc[1][ns] = __builtin_amdgcn_mfma_f32_16x16x32_bf16(al1, bh, acc[1][ns], 0, 0, 0);
      }
    }
    __builtin_amdgcn_s_setprio(0);
    xa = na; xb = nb;
  }
  __syncthreads();   // full drain before overlaying W/EX buffers

  // ---- epilogue: bias, scatter q(split,scaled)/k(split)/v(VT bf16)
#pragma unroll
  for (int ns = 0; ns < 6; ++ns) {
    int cc = (ns * 2 + wn) * 16 + ln;
    int sec = cc >> 6, dd = cc & 63;
    float bias = qkv_b[sec * DM + h * 64 + dd];
#pragma unroll
    for (int sm = 0; sm < 2; ++sm) {
#pragma unroll
      for (int r = 0; r < 4; ++r) {
        int m = wm * 32 + sm * 16 + 4 * g + r;
        float val = acc[sm][ns][r] + bias;
        if (cc < 64) {
          val *= 0.125f;
          unsigned short hi, lo; bf_split_fast(val, hi, lo);
          int byte = m * 128 + (((dd >> 3) ^ (m & 7)) << 4) + ((dd & 7) << 1);
          *(unsigned short*)(smem + QH_OFF + byte) = hi;
          *(unsigned short*)(smem + QL_OFF + byte) = lo;
        } else if (cc < 128) {
          unsigned short hi, lo; bf_split_fast(val, hi, lo);
          int byte = m * 128 + (((dd >> 3) ^ (m & 7)) << 4) + ((dd & 7) << 1);
          *(unsigned short*)(smem + KH_OFF + byte) = hi;
          *(unsigned short*)(smem + KL_OFF + byte) = lo;
        } else {
          int byte = dd * 256 + ((((m >> 3) ^ (dd & 15))) << 4) + ((m & 7) << 1);
          *(unsigned short*)(smem + VT_OFF + byte) = bf_rne_fast(val);
        }
      }
    }
  }
  __syncthreads();

  // ---- Phase B: S = q @ k^T (split 3-pass), wave w owns rows w*16..+16
  const int mB = w * 16;
  f32x4 s2[8];
#pragma unroll
  for (int ns = 0; ns < 8; ++ns) s2[ns] = (f32x4){0.f, 0.f, 0.f, 0.f};
#pragma unroll
  for (int ks = 0; ks < 2; ++ks) {
    int arow = mB + ln;
    int abyte = arow * 128 + (((ks * 4 + g) ^ (arow & 7)) << 4);
    bf16x8 qh = *(const bf16x8*)(smem + QH_OFF + abyte);
    bf16x8 ql = *(const bf16x8*)(smem + QL_OFF + abyte);
#pragma unroll
    for (int ns = 0; ns < 8; ++ns) {
      int brow = ns * 16 + ln;
      int bbyte = brow * 128 + (((ks * 4 + g) ^ (brow & 7)) << 4);
      bf16x8 kh = *(const bf16x8*)(smem + KH_OFF + bbyte);
      bf16x8 kl = *(const bf16x8*)(smem + KL_OFF + bbyte);
      s2[ns] = __builtin_amdgcn_mfma_f32_16x16x32_bf16(qh, kh, s2[ns], 0, 0, 0);
      s2[ns] = __builtin_amdgcn_mfma_f32_16x16x32_bf16(qh, kl, s2[ns], 0, 0, 0);
      s2[ns] = __builtin_amdgcn_mfma_f32_16x16x32_bf16(ql, kh, s2[ns], 0, 0, 0);
    }
  }
  __syncthreads();   // q/k dead; P may overlay

  // ---- Phase C: softmax -> prune -> mask/eb -> softmax -> P (bf16)
  const float* mk = mask + (size_t)(bn & 127) * (WT * WT);
  const float* eb = edge_bias + (size_t)h * (WT * WT);
#pragma unroll
  for (int r = 0; r < 4; ++r) {
    int m = mB + 4 * g + r;
    float sv[8];
#pragma unroll
    for (int ns = 0; ns < 8; ++ns) sv[ns] = s2[ns][r];
    float m1 = sv[0];
#pragma unroll
    for (int ns = 1; ns < 8; ++ns) m1 = fmaxf(m1, sv[ns]);
#pragma unroll
    for (int off = 1; off < 16; off <<= 1) m1 = fmaxf(m1, __shfl_xor(m1, off, 64));
    float e[8], sum1 = 0.f;
#pragma unroll
    for (int ns = 0; ns < 8; ++ns) { e[ns] = __expf(sv[ns] - m1); sum1 += e[ns]; }
#pragma unroll
    for (int off = 1; off < 16; off <<= 1) sum1 += __shfl_xor(sum1, off, 64);
    float thr = 0.5f * sum1;
    float tv[8];
#pragma unroll
    for (int ns = 0; ns < 8; ++ns) {
      int col = ns * 16 + ln;
      float mkv = mk[m * WT + col];
      float ebv = eb[m * WT + col];
      float keep = (e[ns] > thr) ? 0.f : 1.f;
      float val = sv[ns] * keep * mkv * ebv;
      tv[ns] = (val == 0.f) ? -10000.f : val;
    }
    float m2 = tv[0];
#pragma unroll
    for (int ns = 1; ns < 8; ++ns) m2 = fmaxf(m2, tv[ns]);
#pragma unroll
    for (int off = 1; off < 16; off <<= 1) m2 = fmaxf(m2, __shfl_xor(m2, off, 64));
    float e2[8], sum2 = 0.f;
#pragma unroll
    for (int ns = 0; ns < 8; ++ns) { e2[ns] = __expf(tv[ns] - m2); sum2 += e2[ns]; }
#pragma unroll
    for (int off = 1; off < 16; off <<= 1) sum2 += __shfl_xor(sum2, off, 64);
    float inv = 1.f / sum2;
#pragma unroll
    for (int ns = 0; ns < 8; ++ns)
      *(unsigned short*)(smem + P_OFF + m * 272 + (ns * 16 + ln) * 2) = bf_rne_fast(e2[ns] * inv);
  }
  __syncthreads();

  // ---- Phase D: out = P @ v  (plain bf16)
  f32x4 o4[4];
#pragma unroll
  for (int ns = 0; ns < 4; ++ns) o4[ns] = (f32x4){0.f, 0.f, 0.f, 0.f};
#pragma unroll
  for (int ks = 0; ks < 4; ++ks) {
    bf16x8 pa = *(const bf16x8*)(smem + P_OFF + (mB + ln) * 272 + ks * 64 + g * 16);
#pragma unroll
    for (int ns = 0; ns < 4; ++ns) {
      int d = ns * 16 + ln;
      bf16x8 vb = *(const bf16x8*)(smem + VT_OFF + d * 256 + (((ks * 4 + g) ^ (d & 15)) << 4));
      o4[ns] = __builtin_amdgcn_mfma_f32_16x16x32_bf16(pa, vb, o4[ns], 0, 0, 0);
    }
  }
#pragma unroll
  for (int ns = 0; ns < 4; ++ns)
#pragma unroll
    for (int r = 0; r < 4; ++r)
      out[(size_t)bn * (WT * DM) + (size_t)(mB + 4 * g + r) * DM + h * 64 + ns * 16 + ln] = o4[ns][r];
}

// ---------------- proj (PRE path): 64-row blocks, lazy A staging, W via gl_lds
// LDS: W dbuf 2 x 49152 @0 ; A dbuf 2 x 4096 @98304   (106496 total)
__global__ __launch_bounds__(512) void proj_kernel_pre(
    const float* src, const unsigned char* __restrict__ wimg,
    const float* __restrict__ pb, float* dst)
{
  __shared__ __align__(16) unsigned char smem[106496];
  const int t = threadIdx.x;
  const int lane = t & 63;
  const int w = t >> 6;          // 0..7
  const int g = lane >> 4;
  const int ln = lane & 15;
  const int wm = w & 1;          // 2 m-groups (32 rows each)
  const int wn = w >> 1;         // 4 n-groups (192 cols each)

  const int orig = blockIdx.x;
  const int wg = (orig & 7) * 128 + (orig >> 3);   // 1024 blocks, XCD-contiguous
  const size_t row0 = (size_t)wg * 64;

  // A staging: thread covers row ar, 4 k-elems at ac4*4 within each chunk
  const int ar = t >> 3, ac4 = t & 7;
  const float* asrc = src + (row0 + ar) * DM + ac4 * 4;
  const int abyte = ar * 64 + (((ac4 >> 1) ^ ((ar >> 1) & 3)) << 4) + ((ac4 & 1) << 3);
  int afh[2];
#pragma unroll
  for (int sm = 0; sm < 2; ++sm) {
    int rr = wm * 32 + sm * 16 + ln;
    afh[sm] = rr * 64 + ((g ^ ((rr >> 1) & 3)) << 4);
  }

  // prologue: stage W(0); load A(0), A(1); write A(0) into buf0
  {
    const unsigned char* sW = wimg + t * 16;
#pragma unroll
    for (int i = 0; i < 6; ++i) gl_lds16(sW + i * 8192, smem + t * 16 + i * 8192);
  }
  __builtin_amdgcn_sched_barrier(0);
  float4 a0 = *(const float4*)asrc;
  float4 a1 = *(const float4*)(asrc + 32);
  {
    uint2 wv; wv.x = cvt_pk_bf16(a0.x, a0.y); wv.y = cvt_pk_bf16(a0.z, a0.w);
    *(uint2*)(smem + 98304 + abyte) = wv;
  }
  __builtin_amdgcn_sched_barrier(0);

  f32x4 acc[2][12];
#pragma unroll
  for (int i = 0; i < 2; ++i)
#pragma unroll
    for (int j = 0; j < 12; ++j) acc[i][j] = (f32x4){0.f, 0.f, 0.f, 0.f};

  for (int c = 0; c < 24; ++c) {
    // (a) issue A(c+2) load
    float4 a2;
    if (c < 22) a2 = *(const float4*)(asrc + (c + 2) * 32);
    __builtin_amdgcn_sched_barrier(0);
    // (b) cvt + write A(c+1) into buf (c+1)&1
    if (c < 23) {
      uint2 wv; wv.x = cvt_pk_bf16(a1.x, a1.y); wv.y = cvt_pk_bf16(a1.z, a1.w);
      *(uint2*)(smem + 98304 + ((c + 1) & 1) * 4096 + abyte) = wv;
    }
    __builtin_amdgcn_sched_barrier(0);
    // (c) retire own W(c) DMA (keep A(c+2) in flight), drain LDS writes, barrier
    if (c < 22) asm volatile("s_waitcnt vmcnt(1)" ::: "memory");
    else        asm volatile("s_waitcnt vmcnt(0)" ::: "memory");
    asm volatile("s_waitcnt lgkmcnt(0)" ::: "memory");
    __builtin_amdgcn_s_barrier();
    __builtin_amdgcn_sched_barrier(0);
    // (d) stage W(c+1)
    if (c < 23) {
      const unsigned char* sW = wimg + (size_t)(c + 1) * PWCHUNK + t * 16;
      unsigned char* dW = smem + ((c + 1) & 1) * PWCHUNK + t * 16;
#pragma unroll
      for (int i = 0; i < 6; ++i) gl_lds16(sW + i * 8192, dW + i * 8192);
    }
    __builtin_amdgcn_sched_barrier(0);
    // (e) MFMA
    const unsigned char* WB = smem + (c & 1) * PWCHUNK;
    const unsigned char* AB = smem + 98304 + (c & 1) * 4096;
    bf16x8 af0 = *(const bf16x8*)(AB + afh[0]);
    bf16x8 af1 = *(const bf16x8*)(AB + afh[1]);
    __builtin_amdgcn_s_setprio(1);
#pragma unroll
    for (int ns = 0; ns < 12; ++ns) {
      int n = wn * 192 + ns * 16 + ln;
      bf16x8 bfrag = *(const bf16x8*)(WB + n * 64 + ((g ^ ((n >> 1) & 3)) << 4));
      acc[0][ns] = __builtin_amdgcn_mfma_f32_16x16x32_bf16(af0, bfrag, acc[0][ns], 0, 0, 0);
      acc[1][ns] = __builtin_amdgcn_mfma_f32_16x16x32_bf16(af1, bfrag, acc[1][ns], 0, 0, 0);
    }
    __builtin_amdgcn_s_setprio(0);
    a1 = a2;
  }

  // epilogue: bias + store (only this block's own rows -> in-place safe)
#pragma unroll
  for (int ns = 0; ns < 12; ++ns) {
    int col = wn * 192 + ns * 16 + ln;
    float pbv = pb[col];
#pragma unroll
    for (int sm = 0; sm < 2; ++sm)
#pragma unroll
      for (int r = 0; r < 4; ++r)
        dst[(row0 + wm * 32 + sm * 16 + 4 * g + r) * DM + col] = acc[sm][ns][r] + pbv;
  }
}

// ---------------- attn fallback (round-2 verified): used if ws too small ------
__global__ __launch_bounds__(512, 2) void attn_kernel_fb(
    const float* __restrict__ x, const float* __restrict__ qkv_w,
    const float* __restrict__ qkv_b, const float* __restrict__ edge_bias,
    const float* __restrict__ mask, float* __restrict__ out)
{
  __shared__ __align__(16) unsigned char smem[98304];
  const int t = threadIdx.x;
  const int lane = t & 63;
  const int w = t >> 6;
  const int g = lane >> 4;
  const int ln = lane & 15;
  const int wm = w & 3;
  const int wn = w >> 2;

  const int orig = blockIdx.x;
  const int wg = (orig & 7) * 768 + (orig >> 3);
  const int h = wg % 12;
  const int bn = wg / 12;

  const float* xw = x + (size_t)bn * (WT * DM);

  f32x4 acc[2][6];
#pragma unroll
  for (int i = 0; i < 2; ++i)
#pragma unroll
    for (int j = 0; j < 6; ++j) acc[i][j] = (f32x4){0.f, 0.f, 0.f, 0.f};

  float4 wreg[6], xreg[8];
#pragma unroll
  for (int q = 0; q < 6; ++q) {
    int fid = q * 512 + t;
    int j = fid >> 4, c4 = fid & 15;
    int sec = j >> 6, d = j & 63;
    wreg[q] = *(const float4*)(qkv_w + (size_t)(sec * DM + h * 64 + d) * DM + c4 * 4);
  }

  for (int c = 0; c < 12; ++c) {
    const int kc = c * 64;
#pragma unroll
    for (int sm = 0; sm < 2; ++sm)
#pragma unroll
      for (int ks = 0; ks < 2; ++ks) {
        int row = wm * 32 + sm * 16 + ln;
        const float* p = xw + (size_t)row * DM + kc + ks * 32 + g * 8;
        xreg[(sm * 2 + ks) * 2 + 0] = *(const float4*)p;
        xreg[(sm * 2 + ks) * 2 + 1] = *(const float4*)(p + 4);
      }
    unsigned char* WH = smem + (c & 1) * 49152;
    unsigned char* WL = WH + 24576;
#pragma unroll
    for (int q = 0; q < 6; ++q) {
      int fid = q * 512 + t;
      int j = fid >> 4, c4 = fid & 15;
      int byte = j * 128 + ((((c4 >> 1) ^ (j & 7))) << 4) + ((c4 & 1) << 3);
      float4 v = wreg[q];
      unsigned short h0, h1, h2, h3, l0, l1, l2, l3;
      bf_split(v.x, h0, l0); bf_split(v.y, h1, l1);
      bf_split(v.z, h2, l2); bf_split(v.w, h3, l3);
      uint2 hv, lv;
      hv.x = (unsigned)h0 | ((unsigned)h1 << 16); hv.y = (unsigned)h2 | ((unsigned)h3 << 16);
      lv.x = (unsigned)l0 | ((unsigned)l1 << 16); lv.y = (unsigned)l2 | ((unsigned)l3 << 16);
      *(uint2*)(WH + byte) = hv;
      *(uint2*)(WL + byte) = lv;
    }
    if (c < 11) {
#pragma unroll
      for (int q = 0; q < 6; ++q) {
        int fid = q * 512 + t;
        int j = fid >> 4, c4 = fid & 15;
        int sec = j >> 6, d = j & 63;
        wreg[q] = *(const float4*)(qkv_w + (size_t)(sec * DM + h * 64 + d) * DM + kc + 64 + c4 * 4);
      }
    }
    __syncthreads();
#pragma unroll
    for (int ks = 0; ks < 2; ++ks) {
      bf16x8 ah[2], al[2];
#pragma unroll
      for (int sm = 0; sm < 2; ++sm)
        split8(xreg[(sm * 2 + ks) * 2 + 0], xreg[(sm * 2 + ks) * 2 + 1], ah[sm], al[sm]);
#pragma unroll
      for (int ns = 0; ns < 6; ++ns) {
        int j = wn * 96 + ns * 16 + ln;
        int sw = j * 128 + (((ks * 4 + g) ^ (j & 7)) << 4);
        bf16x8 bh = *(const bf16x8*)(WH + sw);
        bf16x8 bl = *(const bf16x8*)(WL + sw);
#pragma unroll
        for (int sm = 0; sm < 2; ++sm) {
          acc[sm][ns] = __builtin_amdgcn_mfma_f32_16x16x32_bf16(ah[sm], bh, acc[sm][ns], 0, 0, 0);
          acc[sm][ns] = __builtin_amdgcn_mfma_f32_16x16x32_bf16(ah[sm], bl, acc[sm][ns], 0, 0, 0);
          acc[sm][ns] = __builtin_amdgcn_mfma_f32_16x16x32_bf16(al[sm], bh, acc[sm][ns], 0, 0, 0);
        }
      }
    }
  }
  __syncthreads();

#pragma unroll
  for (int sm = 0; sm < 2; ++sm)
#pragma unroll
    for (int ns = 0; ns < 6; ++ns) {
      int cc = wn * 96 + ns * 16 + ln;
      int sec = cc >> 6, dd = cc & 63;
      float bias = qkv_b[sec * DM + h * 64 + dd];
#pragma unroll
      for (int r = 0; r < 4; ++r) {
        int m = wm * 32 + sm * 16 + 4 * g + r;
        float val = acc[sm][ns][r] + bias;
        if (cc < 64) {
          val *= 0.125f;
          unsigned short hi, lo; bf_split(val, hi, lo);
          int byte = m * 128 + ((((dd >> 3) ^ (m & 7))) << 4) + ((dd & 7) << 1);
          *(unsigned short*)(smem + QH_OFF + byte) = hi;
          *(unsigned short*)(smem + QL_OFF + byte) = lo;
        } else if (cc < 128) {
          unsigned short hi, lo; bf_split(val, hi, lo);
          int byte = m * 128 + ((((dd >> 3) ^ (m & 7))) << 4) + ((dd & 7) << 1);
          *(unsigned short*)(smem + KH_OFF + byte) = hi;
          *(unsigned short*)(smem + KL_OFF + byte) = lo;
        } else {
          *(unsigned short*)(smem + VT_OFF + dd * 272 + m * 2) = bf_rne(val);
        }
      }
    }
  __syncthreads();

  const int mB = w * 16;
  f32x4 s2[8];
#pragma unroll
  for (int ns = 0; ns < 8; ++ns) s2[ns] = (f32x4){0.f, 0.f, 0.f, 0.f};
#pragma unroll
  for (int ks = 0; ks < 2; ++ks) {
    int arow = mB + ln;
    int abyte = arow * 128 + (((ks * 4 + g) ^ (arow & 7)) << 4);
    bf16x8 qh = *(const bf16x8*)(smem + QH_OFF + abyte);
    bf16x8 ql = *(const bf16x8*)(smem + QL_OFF + abyte);
#pragma unroll
    for (int ns = 0; ns < 8; ++ns) {
      int brow = ns * 16 + ln;
      int bbyte = brow * 128 + (((ks * 4 + g) ^ (brow & 7)) << 4);
      bf16x8 kh = *(const bf16x8*)(smem + KH_OFF + bbyte);
      bf16x8 kl = *(const bf16x8*)(smem + KL_OFF + bbyte);
      s2[ns] = __builtin_amdgcn_mfma_f32_16x16x32_bf16(qh, kh, s2[ns], 0, 0, 0);
      s2[ns] = __builtin_amdgcn_mfma_f32_16x16x32_bf16(qh, kl, s2[ns], 0, 0, 0);
      s2[ns] = __builtin_amdgcn_mfma_f32_16x16x32_bf16(ql, kh, s2[ns], 0, 0, 0);
    }
  }
  __syncthreads();

  const float* mk = mask + (size_t)(bn & 127) * (WT * WT);
  const float* eb = edge_bias + (size_t)h * (WT * WT);
#pragma unroll
  for (int r = 0; r < 4; ++r) {
    int m = mB + 4 * g + r;
    float sv[8];
#pragma unroll
    for (int ns = 0; ns < 8; ++ns) sv[ns] = s2[ns][r];
    float m1 = sv[0];
#pragma unroll
    for (int ns = 1; ns < 8; ++ns) m1 = fmaxf(m1, sv[ns]);
#pragma unroll
    for (int off = 1; off < 16; off <<= 1) m1 = fmaxf(m1, __shfl_xor(m1, off, 64));
    float e[8], sum1 = 0.f;
#pragma unroll
    for (int ns = 0; ns < 8; ++ns) { e[ns] = __expf(sv[ns] - m1); sum1 += e[ns]; }
#pragma unroll
    for (int off = 1; off < 16; off <<= 1) sum1 += __shfl_xor(sum1, off, 64);
    float thr = 0.5f * sum1;
    float tv[8];
#pragma unroll
    for (int ns = 0; ns < 8; ++ns) {
      int col = ns * 16 + ln;
      float mkv = mk[m * WT + col];
      float ebv = eb[m * WT + col];
      float keep = (e[ns] > thr) ? 0.f : 1.f;
      float val = sv[ns] * keep * mkv * ebv;
      tv[ns] = (val == 0.f) ? -10000.f : val;
    }
    float m2 = tv[0];
#pragma unroll
    for (int ns = 1; ns < 8; ++ns) m2 = fmaxf(m2, tv[ns]);
#pragma unroll
    for (int off = 1; off < 16; off <<= 1) m2 = fmaxf(m2, __shfl_xor(m2, off, 64));
    float e2[8], sum2 = 0.f;
#pragma unroll
    for (int ns = 0; ns < 8; ++ns) { e2[ns] = __expf(tv[ns] - m2); sum2 += e2[ns]; }
#pragma unroll
    for (int off = 1; off < 16; off <<= 1) sum2 += __shfl_xor(sum2, off, 64);
    float inv = 1.f / sum2;
#pragma unroll
    for (int ns = 0; ns < 8; ++ns)
      *(unsigned short*)(smem + P_OFF + m * 272 + (ns * 16 + ln) * 2) = bf_rne(e2[ns] * inv);
  }
  __syncthreads();

  f32x4 o4[4];
#pragma unroll
  for (int ns = 0; ns < 4; ++ns) o4[ns] = (f32x4){0.f, 0.f, 0.f, 0.f};
#pragma unroll
  for (int ks = 0; ks < 4; ++ks) {
    bf16x8 pa = *(const bf16x8*)(smem + P_OFF + (mB + ln) * 272 + ks * 64 + g * 16);
#pragma unroll
    for (int ns = 0; ns < 4; ++ns) {
      bf16x8 vb = *(const bf16x8*)(smem + VT_OFF + (ns * 16 + ln) * 272 + ks * 64 + g * 16);
      o4[ns] = __builtin_amdgcn_mfma_f32_16x16x32_bf16(pa, vb, o4[ns], 0, 0, 0);
    }
  }
#pragma unroll
  for (int ns = 0; ns < 4; ++ns)
#pragma unroll
    for (int r = 0; r < 4; ++r)
      out[(size_t)bn * (WT * DM) + (size_t)(mB + 4 * g + r) * DM + h * 64 + ns * 16 + ln] = o4[ns][r];
}

// ---------------- proj fallback: round-2/3 verified 64-row version ------------
#define PA_OFF 0
#define PW_OFF 98304

__global__ __launch_bounds__(512, 2) void proj_kernel_fb(
    const float* src, const float* __restrict__ pw,
    const float* __restrict__ pb, float* dst)
{
  __shared__ __align__(16) unsigned char smem[147456];
  const int t = threadIdx.x;
  const int lane = t & 63;
  const int w = t >> 6;
  const int g = lane >> 4;
  const int ln = lane & 15;
  const int wm = w & 1;
  const int wn = w >> 1;

  const int orig = blockIdx.x;
  const int wg = (orig & 7) * 128 + (orig >> 3);
  const size_t row0 = (size_t)wg * 64;

#pragma unroll
  for (int q = 0; q < 24; ++q) {
    int fid = q * 512 + t;
    int row = fid / 192, c4 = fid % 192;
    float4 v = *(const float4*)(src + (row0 + row) * DM + c4 * 4);
    int slot = c4 >> 1;
    int byte = row * 1536 + (((slot & ~7) | ((slot & 7) ^ (row & 7))) << 4) + ((c4 & 1) << 3);
    uint2 hv;
    hv.x = (unsigned)bf_rne(v.x) | ((unsigned)bf_rne(v.y) << 16);
    hv.y = (unsigned)bf_rne(v.z) | ((unsigned)bf_rne(v.w) << 16);
    *(uint2*)(smem + PA_OFF + byte) = hv;
  }

  f32x4 accp[2][12];
#pragma unroll
  for (int i = 0; i < 2; ++i)
#pragma unroll
    for (int j = 0; j < 12; ++j) accp[i][j] = (f32x4){0.f, 0.f, 0.f, 0.f};

  for (int c = 0; c < 24; ++c) {
    const int kc = c * 32;
    __syncthreads();
#pragma unroll
    for (int q = 0; q < 12; ++q) {
      int fid = q * 512 + t;
      int n = fid >> 3, c4 = fid & 7;
      float4 v = *(const float4*)(pw + (size_t)n * DM + kc + c4 * 4);
      int slot = (n & 1) * 4 + (c4 >> 1);
      int byte = (n >> 1) * 128 + ((slot ^ ((n >> 1) & 7)) << 4) + ((c4 & 1) << 3);
      uint2 hv;
      hv.x = (unsigned)bf_rne(v.x) | ((unsigned)bf_rne(v.y) << 16);
      hv.y = (unsigned)bf_rne(v.z) | ((unsigned)bf_rne(v.w) << 16);
      *(uint2*)(smem + PW_OFF + byte) = hv;
    }
    __syncthreads();
    bf16x8 af[2];
#pragma unroll
    for (int sm = 0; sm < 2; ++sm) {
      int row = wm * 32 + sm * 16 + ln;
      int slot = (kc >> 3) + g;
      int byte = row * 1536 + (((slot & ~7) | ((slot & 7) ^ (row & 7))) << 4);
      af[sm] = *(const bf16x8*)(smem + PA_OFF + byte);
    }
#pragma unroll
    for (int j = 0; j < 12; ++j) {
      int n = (wn * 12 + j) * 16 + ln;
      int slot = (n & 1) * 4 + g;
      bf16x8 bf_ = *(const bf16x8*)(smem + PW_OFF + (n >> 1) * 128 + ((slot ^ ((n >> 1) & 7)) << 4));
#pragma unroll
      for (int sm = 0; sm < 2; ++sm)
        accp[sm][j] = __builtin_amdgcn_mfma_f32_16x16x32_bf16(af[sm], bf_, accp[sm][j], 0, 0, 0);
    }
  }

#pragma unroll
  for (int j = 0; j < 12; ++j) {
    int col = (wn * 12 + j) * 16 + ln;
    float pbv = pb[col];
#pragma unroll
    for (int sm = 0; sm < 2; ++sm)
#pragma unroll
      for (int r = 0; r < 4; ++r)
        dst[(row0 + wm * 32 + sm * 16 + 4 * g + r) * DM + col] = accp[sm][j][r] + pbv;
  }
}

extern "C" void kernel_launch(void* const* d_in, const int* in_sizes, int n_in,
                              void* d_out, int out_size, void* d_ws, size_t ws_size,
                              hipStream_t stream) {
  const float* x         = (const float*)d_in[0];
  const float* qkv_w     = (const float*)d_in[1];
  const float* qkv_b     = (const float*)d_in[2];
  const float* proj_w    = (const float*)d_in[3];
  const float* proj_b    = (const float*)d_in[4];
  const float* edge_bias = (const float*)d_in[5];
  const float* mask      = (const float*)d_in[6];
  float* out = (float*)d_out;

  const bool p1 = (d_ws != nullptr) && (ws_size >= WS_W1);
  const bool p2 = (d_ws != nullptr) && (ws_size >= WS_W1 + WS_W2);
  unsigned char* wsW = (unsigned char*)d_ws;
  unsigned char* wsP = wsW + WS_W1;

  if (p1) {
    split_w_kernel<<<1728, 256, 0, stream>>>(qkv_w, wsW);
  }
  if (p2) {
    split_pw_kernel<<<576, 256, 0, stream>>>(proj_w, wsP);
  }
  if (p1) {
    attn_kernel_pre<<<NW * NH, 512, 0, stream>>>(x, wsW, qkv_b, edge_bias, mask, out);
  } else {
    attn_kernel_fb<<<NW * NH, 512, 0, stream>>>(x, qkv_w, qkv_b, edge_bias, mask, out);
  }
  if (p2) {
    proj_kernel_pre<<<1024, 512, 0, stream>>>(out, wsP, proj_b, out);
  } else {
    proj_kernel_fb<<<1024, 512, 0, stream>>>(out, proj_w, proj_b, out);
  }
}

// Round 6
// 706.520 us; speedup vs baseline: 10.4636x; 1.1721x over previous
//
#include <hip/hip_runtime.h>

#define NW 512
#define WT 128
#define DM 768
#define NH 12

typedef __attribute__((ext_vector_type(8))) short bf16x8;
typedef __attribute__((ext_vector_type(4))) float f32x4;
typedef __attribute__((ext_vector_type(4))) unsigned int u32x4;

#define W1CH 12288                            // one (head,chunk) attn W image (single bf16)
#define WS_W1 ((size_t)NH * 24 * W1CH)        // 3,538,944 attn W images
#define PWCHUNK 49152                         // one proj W k32 chunk image
#define WS_W2 ((size_t)24 * PWCHUNK)          // 1,179,648 proj W image

__device__ __forceinline__ unsigned short bf_rne(float v) {
  unsigned u = __float_as_uint(v);
  unsigned r = u + 0x7fffu + ((u >> 16) & 1u);
  return (unsigned short)(r >> 16);
}
__device__ __forceinline__ void bf_split(float v, unsigned short& hi, unsigned short& lo) {
  hi = bf_rne(v);
  float hf = __uint_as_float(((unsigned)hi) << 16);
  lo = bf_rne(v - hf);
}

// packed RNE f32->bf16 pair: lo16 = bf16(a), hi16 = bf16(b)
__device__ __forceinline__ unsigned cvt_pk_bf16(float a, float b) {
  unsigned r;
  asm("v_cvt_pk_bf16_f32 %0, %1, %2" : "=v"(r) : "v"(a), "v"(b));
  return r;
}
__device__ __forceinline__ unsigned short bf_rne_fast(float v) {
  return (unsigned short)cvt_pk_bf16(v, v);
}
__device__ __forceinline__ void bf_split_fast(float v, unsigned short& hi, unsigned short& lo) {
  unsigned hp = cvt_pk_bf16(v, v);
  float hf = __uint_as_float(hp << 16);
  lo = (unsigned short)cvt_pk_bf16(v - hf, v - hf);
  hi = (unsigned short)hp;
}

// split 8 floats into 2-term bf16 (RNE hi, RNE lo) via cvt_pk
__device__ __forceinline__ void split8(float4 v0, float4 v1, bf16x8& hi, bf16x8& lo) {
  float f[8] = {v0.x, v0.y, v0.z, v0.w, v1.x, v1.y, v1.z, v1.w};
  u32x4 hu, lu;
#pragma unroll
  for (int i = 0; i < 4; ++i) {
    float e0 = f[2 * i], e1 = f[2 * i + 1];
    unsigned hp = cvt_pk_bf16(e0, e1);
    float h0 = __uint_as_float(hp << 16);
    float h1 = __uint_as_float(hp & 0xffff0000u);
    lu[i] = cvt_pk_bf16(e0 - h0, e1 - h1);
    hu[i] = hp;
  }
  hi = __builtin_bit_cast(bf16x8, hu);
  lo = __builtin_bit_cast(bf16x8, lu);
}

__device__ __forceinline__ void gl_lds16(const void* g, void* l) {
  __builtin_amdgcn_global_load_lds(
      (const __attribute__((address_space(1))) void*)g,
      (__attribute__((address_space(3))) void*)l, 16, 0, 0);
}

// image row byte layout (shared by attn W and proj W images):
//   byte(j, c4) = j*64 + (((c4>>1) ^ ((j>>1)&3))<<4) + ((c4&1)<<3)
// frag read (k-slice g): j*64 + ((g ^ ((j>>1)&3))<<4)  -> 2-way banks (free)

// ---------------- precompute: attn W -> single-bf16 swizzled LDS images ----
__global__ __launch_bounds__(256) void split_w_kernel(
    const float* __restrict__ qkv_w, unsigned char* __restrict__ wsW)
{
  int id = blockIdx.x * 256 + threadIdx.x;      // 442368 total
  int c4 = id & 7;
  int j  = (id >> 3) % 192;
  int hc = (id >> 3) / 192;                     // h*24 + c
  int c  = hc % 24;
  int h  = hc / 24;
  int sec = j >> 6, d = j & 63;
  const float* src = qkv_w + (size_t)(sec * DM + h * 64 + d) * DM + c * 32 + c4 * 4;
  float4 v = *(const float4*)src;
  uint2 hv;
  hv.x = (unsigned)bf_rne(v.x) | ((unsigned)bf_rne(v.y) << 16);
  hv.y = (unsigned)bf_rne(v.z) | ((unsigned)bf_rne(v.w) << 16);
  int byte = j * 64 + (((c4 >> 1) ^ ((j >> 1) & 3)) << 4) + ((c4 & 1) << 3);
  *(uint2*)(wsW + (size_t)hc * W1CH + byte) = hv;
}

// ---------------- precompute: proj W -> bf16 swizzled LDS image ------------
__global__ __launch_bounds__(256) void split_pw_kernel(
    const float* __restrict__ pw, unsigned char* __restrict__ wsP)
{
  int id = blockIdx.x * 256 + threadIdx.x;      // 147456 total
  int c4 = id & 7;
  int n  = (id >> 3) % 768;
  int c  = (id >> 3) / 768;
  float4 v = *(const float4*)(pw + (size_t)n * DM + c * 32 + c4 * 4);
  uint2 hv;
  hv.x = (unsigned)bf_rne(v.x) | ((unsigned)bf_rne(v.y) << 16);
  hv.y = (unsigned)bf_rne(v.z) | ((unsigned)bf_rne(v.w) << 16);
  int byte = n * 64 + (((c4 >> 1) ^ ((n >> 1) & 3)) << 4) + ((c4 & 1) << 3);
  *(uint2*)(wsP + (size_t)c * PWCHUNK + byte) = hv;
}

// ---------------- attn (PRE path) LDS layout (bytes) ----------------
// Phase A: W dbuf 2 x 12288 @0 ; EX dbuf 2 x 16384 @49152  (81920 total)
// Post-A : QH@0 QL@16384 KH@32768 KL@49152 (each [128]x128B swz)
//          VT@65536: [64 d]x256B
//          P @0: [128]x272B bf16 (overlays QH/QL + 2KB of KH)
#define QH_OFF 0
#define QL_OFF 16384
#define KH_OFF 32768
#define KL_OFF 49152
#define VT_OFF 65536
#define EX_OFF 49152
#define P_OFF  0

__global__ __launch_bounds__(512, 4) void attn_kernel_pre(
    const float* __restrict__ x, const unsigned char* __restrict__ wimg,
    const float* __restrict__ qkv_b, const float* __restrict__ edge_bias,
    const float* __restrict__ mask, float* __restrict__ out)
{
  __shared__ __align__(16) unsigned char smem[81920];
  const int t = threadIdx.x;
  const int lane = t & 63;
  const int w = t >> 6;          // 0..7
  const int g = lane >> 4;       // 0..3
  const int ln = lane & 15;      // 0..15
  const int wm = w & 3;          // m-block (32 rows)
  const int wn = w >> 2;         // strip parity / k-half for x staging

  const int orig = blockIdx.x;
  const int wg = (orig & 7) * 768 + (orig >> 3);   // XCD-contiguous, bijective
  const int h = wg % 12;
  const int bn = wg / 12;

  const float* xw = x + (size_t)bn * (WT * DM);
  const unsigned char* whead = wimg + (size_t)h * (24 * W1CH);

  f32x4 acc[2][6];
#pragma unroll
  for (int i = 0; i < 2; ++i)
#pragma unroll
    for (int j = 0; j < 6; ++j) acc[i][j] = (f32x4){0.f, 0.f, 0.f, 0.f};

  // x half-load: this wave stages rows wm*32+(lane&31), k-half wn*16+(lane>>5)*8
  const int exr = wm * 32 + (lane & 31);
  const int exs = wn * 2 + (lane >> 5);
  const float* xptr = xw + (size_t)exr * DM + wn * 16 + (lane >> 5) * 8;
  const int ex_w_hi = exr * 128 + ((exs ^ (exr & 7)) << 4);
  const int ex_w_lo = exr * 128 + (((exs + 4) ^ (exr & 7)) << 4);
  int ex_r_h[2], ex_r_l[2];
#pragma unroll
  for (int sm = 0; sm < 2; ++sm) {
    int rr = wm * 32 + sm * 16 + ln;
    ex_r_h[sm] = rr * 128 + ((g ^ (rr & 7)) << 4);
    ex_r_l[sm] = rr * 128 + (((g + 4) ^ (rr & 7)) << 4);
  }

  // prologue: stage W(0) into buf0 (12288 B: all threads + waves 0-3), then x(0)
  {
    gl_lds16(whead + t * 16, smem + t * 16);
    if (t < 256) gl_lds16(whead + 8192 + t * 16, smem + 8192 + t * 16);
  }
  __builtin_amdgcn_sched_barrier(0);
  float4 xa = *(const float4*)xptr;
  float4 xb = *(const float4*)(xptr + 4);
  __builtin_amdgcn_sched_barrier(0);

  for (int c = 0; c < 24; ++c) {
    // (a) issue x(c+1) loads
    float4 na, nb;
    if (c < 23) {
      na = *(const float4*)(xptr + (c + 1) * 32);
      nb = *(const float4*)(xptr + (c + 1) * 32 + 4);
    }
    __builtin_amdgcn_sched_barrier(0);
    // (b) split x(c) (compiler waits x(c)) + exchange writes
    bf16x8 xh8, xl8;
    split8(xa, xb, xh8, xl8);
    unsigned char* exb = smem + EX_OFF + (c & 1) * 16384;
    *(bf16x8*)(exb + ex_w_hi) = xh8;
    *(bf16x8*)(exb + ex_w_lo) = xl8;
    __builtin_amdgcn_sched_barrier(0);
    // (c) retire own W(c) DMA (keep x(c+1) in flight), drain LDS writes, barrier
    if (c < 23) asm volatile("s_waitcnt vmcnt(2)" ::: "memory");
    else        asm volatile("s_waitcnt vmcnt(0)" ::: "memory");
    asm volatile("s_waitcnt lgkmcnt(0)" ::: "memory");
    __builtin_amdgcn_s_barrier();
    __builtin_amdgcn_sched_barrier(0);
    // (d) stage W(c+1) into other buffer
    if (c < 23) {
      const unsigned char* src = whead + (size_t)(c + 1) * W1CH;
      unsigned char* dst = smem + ((c + 1) & 1) * W1CH;
      gl_lds16(src + t * 16, dst + t * 16);
      if (t < 256) gl_lds16(src + 8192 + t * 16, dst + 8192 + t * 16);
    }
    __builtin_amdgcn_sched_barrier(0);
    // (e) fragments + MFMA (2-pass q/k, 1-pass v)
    const unsigned char* WH = smem + (c & 1) * W1CH;
    bf16x8 ah0 = *(const bf16x8*)(exb + ex_r_h[0]);
    bf16x8 al0 = *(const bf16x8*)(exb + ex_r_l[0]);
    bf16x8 ah1 = *(const bf16x8*)(exb + ex_r_h[1]);
    bf16x8 al1 = *(const bf16x8*)(exb + ex_r_l[1]);
    __builtin_amdgcn_s_setprio(1);
    // strips: cc = (ns*2+wn)*16+ln ; ns<4 -> q/k (2-pass), ns>=4 -> v (1-pass)
#pragma unroll
    for (int ns = 0; ns < 6; ++ns) {
      int j = (ns * 2 + wn) * 16 + ln;
      int sw = j * 64 + ((g ^ ((j >> 1) & 3)) << 4);
      bf16x8 bh = *(const bf16x8*)(WH + sw);
      acc[0][ns] = __builtin_amdgcn_mfma_f32_16x16x32_bf16(ah0, bh, acc[0][ns], 0, 0, 0);
      acc[1][ns] = __builtin_amdgcn_mfma_f32_16x16x32_bf16(ah1, bh, acc[1][ns], 0, 0, 0);
      if (ns < 4) {
        acc[0][ns] = __builtin_amdgcn_mfma_f32_16x16x32_bf16(al0, bh, acc[0][ns], 0, 0, 0);
        acc[1][ns] = __builtin_amdgcn_mfma_f32_16x16x32_bf16(al1, bh, acc[1][ns], 0, 0, 0);
      }
    }
    __builtin_amdgcn_s_setprio(0);
    xa = na; xb = nb;
  }
  __syncthreads();   // full drain before overlaying W/EX buffers

  // ---- epilogue: bias, scatter q(split,scaled)/k(split)/v(VT bf16)
#pragma unroll
  for (int ns = 0; ns < 6; ++ns) {
    int cc = (ns * 2 + wn) * 16 + ln;
    int sec = cc >> 6, dd = cc & 63;
    float bias = qkv_b[sec * DM + h * 64 + dd];
#pragma unroll
    for (int sm = 0; sm < 2; ++sm) {
#pragma unroll
      for (int r = 0; r < 4; ++r) {
        int m = wm * 32 + sm * 16 + 4 * g + r;
        float val = acc[sm][ns][r] + bias;
        if (cc < 64) {
          val *= 0.125f;
          unsigned short hi, lo; bf_split_fast(val, hi, lo);
          int byte = m * 128 + (((dd >> 3) ^ (m & 7)) << 4) + ((dd & 7) << 1);
          *(unsigned short*)(smem + QH_OFF + byte) = hi;
          *(unsigned short*)(smem + QL_OFF + byte) = lo;
        } else if (cc < 128) {
          unsigned short hi, lo; bf_split_fast(val, hi, lo);
          int byte = m * 128 + (((dd >> 3) ^ (m & 7)) << 4) + ((dd & 7) << 1);
          *(unsigned short*)(smem + KH_OFF + byte) = hi;
          *(unsigned short*)(smem + KL_OFF + byte) = lo;
        } else {
          int byte = dd * 256 + ((((m >> 3) ^ (dd & 15))) << 4) + ((m & 7) << 1);
          *(unsigned short*)(smem + VT_OFF + byte) = bf_rne_fast(val);
        }
      }
    }
  }
  __syncthreads();

  // ---- Phase B: S = q @ k^T (split 3-pass), wave w owns rows w*16..+16
  const int mB = w * 16;
  f32x4 s2[8];
#pragma unroll
  for (int ns = 0; ns < 8; ++ns) s2[ns] = (f32x4){0.f, 0.f, 0.f, 0.f};
#pragma unroll
  for (int ks = 0; ks < 2; ++ks) {
    int arow = mB + ln;
    int abyte = arow * 128 + (((ks * 4 + g) ^ (arow & 7)) << 4);
    bf16x8 qh = *(const bf16x8*)(smem + QH_OFF + abyte);
    bf16x8 ql = *(const bf16x8*)(smem + QL_OFF + abyte);
#pragma unroll
    for (int ns = 0; ns < 8; ++ns) {
      int brow = ns * 16 + ln;
      int bbyte = brow * 128 + (((ks * 4 + g) ^ (brow & 7)) << 4);
      bf16x8 kh = *(const bf16x8*)(smem + KH_OFF + bbyte);
      bf16x8 kl = *(const bf16x8*)(smem + KL_OFF + bbyte);
      s2[ns] = __builtin_amdgcn_mfma_f32_16x16x32_bf16(qh, kh, s2[ns], 0, 0, 0);
      s2[ns] = __builtin_amdgcn_mfma_f32_16x16x32_bf16(qh, kl, s2[ns], 0, 0, 0);
      s2[ns] = __builtin_amdgcn_mfma_f32_16x16x32_bf16(ql, kh, s2[ns], 0, 0, 0);
    }
  }
  __syncthreads();   // q/k dead; P may overlay

  // ---- Phase C: softmax -> prune -> mask/eb -> softmax -> P (bf16)
  const float* mk = mask + (size_t)(bn & 127) * (WT * WT);
  const float* eb = edge_bias + (size_t)h * (WT * WT);
#pragma unroll
  for (int r = 0; r < 4; ++r) {
    int m = mB + 4 * g + r;
    float sv[8];
#pragma unroll
    for (int ns = 0; ns < 8; ++ns) sv[ns] = s2[ns][r];
    float m1 = sv[0];
#pragma unroll
    for (int ns = 1; ns < 8; ++ns) m1 = fmaxf(m1, sv[ns]);
#pragma unroll
    for (int off = 1; off < 16; off <<= 1) m1 = fmaxf(m1, __shfl_xor(m1, off, 64));
    float e[8], sum1 = 0.f;
#pragma unroll
    for (int ns = 0; ns < 8; ++ns) { e[ns] = __expf(sv[ns] - m1); sum1 += e[ns]; }
#pragma unroll
    for (int off = 1; off < 16; off <<= 1) sum1 += __shfl_xor(sum1, off, 64);
    float thr = 0.5f * sum1;
    float tv[8];
#pragma unroll
    for (int ns = 0; ns < 8; ++ns) {
      int col = ns * 16 + ln;
      float mkv = mk[m * WT + col];
      float ebv = eb[m * WT + col];
      float keep = (e[ns] > thr) ? 0.f : 1.f;
      float val = sv[ns] * keep * mkv * ebv;
      tv[ns] = (val == 0.f) ? -10000.f : val;
    }
    float m2 = tv[0];
#pragma unroll
    for (int ns = 1; ns < 8; ++ns) m2 = fmaxf(m2, tv[ns]);
#pragma unroll
    for (int off = 1; off < 16; off <<= 1) m2 = fmaxf(m2, __shfl_xor(m2, off, 64));
    float e2[8], sum2 = 0.f;
#pragma unroll
    for (int ns = 0; ns < 8; ++ns) { e2[ns] = __expf(tv[ns] - m2); sum2 += e2[ns]; }
#pragma unroll
    for (int off = 1; off < 16; off <<= 1) sum2 += __shfl_xor(sum2, off, 64);
    float inv = 1.f / sum2;
#pragma unroll
    for (int ns = 0; ns < 8; ++ns)
      *(unsigned short*)(smem + P_OFF + m * 272 + (ns * 16 + ln) * 2) = bf_rne_fast(e2[ns] * inv);
  }
  __syncthreads();

  // ---- Phase D: out = P @ v  (plain bf16)
  f32x4 o4[4];
#pragma unroll
  for (int ns = 0; ns < 4; ++ns) o4[ns] = (f32x4){0.f, 0.f, 0.f, 0.f};
#pragma unroll
  for (int ks = 0; ks < 4; ++ks) {
    bf16x8 pa = *(const bf16x8*)(smem + P_OFF + (mB + ln) * 272 + ks * 64 + g * 16);
#pragma unroll
    for (int ns = 0; ns < 4; ++ns) {
      int d = ns * 16 + ln;
      bf16x8 vb = *(const bf16x8*)(smem + VT_OFF + d * 256 + (((ks * 4 + g) ^ (d & 15)) << 4));
      o4[ns] = __builtin_amdgcn_mfma_f32_16x16x32_bf16(pa, vb, o4[ns], 0, 0, 0);
    }
  }
#pragma unroll
  for (int ns = 0; ns < 4; ++ns)
#pragma unroll
    for (int r = 0; r < 4; ++r)
      out[(size_t)bn * (WT * DM) + (size_t)(mB + 4 * g + r) * DM + h * 64 + ns * 16 + ln] = o4[ns][r];
}

// ---------------- proj (PRE path): 64-row blocks, lazy A staging, W via gl_lds
// LDS: W dbuf 2 x 49152 @0 ; A dbuf 2 x 4096 @98304   (106496 total)
__global__ __launch_bounds__(512) void proj_kernel_pre(
    const float* src, const unsigned char* __restrict__ wimg,
    const float* __restrict__ pb, float* dst)
{
  __shared__ __align__(16) unsigned char smem[106496];
  const int t = threadIdx.x;
  const int lane = t & 63;
  const int w = t >> 6;          // 0..7
  const int g = lane >> 4;
  const int ln = lane & 15;
  const int wm = w & 1;          // 2 m-groups (32 rows each)
  const int wn = w >> 1;         // 4 n-groups (192 cols each)

  const int orig = blockIdx.x;
  const int wg = (orig & 7) * 128 + (orig >> 3);   // 1024 blocks, XCD-contiguous
  const size_t row0 = (size_t)wg * 64;

  // A staging: thread covers row ar, 4 k-elems at ac4*4 within each chunk
  const int ar = t >> 3, ac4 = t & 7;
  const float* asrc = src + (row0 + ar) * DM + ac4 * 4;
  const int abyte = ar * 64 + (((ac4 >> 1) ^ ((ar >> 1) & 3)) << 4) + ((ac4 & 1) << 3);
  int afh[2];
#pragma unroll
  for (int sm = 0; sm < 2; ++sm) {
    int rr = wm * 32 + sm * 16 + ln;
    afh[sm] = rr * 64 + ((g ^ ((rr >> 1) & 3)) << 4);
  }

  // prologue: stage W(0); load A(0), A(1); write A(0) into buf0
  {
    const unsigned char* sW = wimg + t * 16;
#pragma unroll
    for (int i = 0; i < 6; ++i) gl_lds16(sW + i * 8192, smem + t * 16 + i * 8192);
  }
  __builtin_amdgcn_sched_barrier(0);
  float4 a0 = *(const float4*)asrc;
  float4 a1 = *(const float4*)(asrc + 32);
  {
    uint2 wv; wv.x = cvt_pk_bf16(a0.x, a0.y); wv.y = cvt_pk_bf16(a0.z, a0.w);
    *(uint2*)(smem + 98304 + abyte) = wv;
  }
  __builtin_amdgcn_sched_barrier(0);

  f32x4 acc[2][12];
#pragma unroll
  for (int i = 0; i < 2; ++i)
#pragma unroll
    for (int j = 0; j < 12; ++j) acc[i][j] = (f32x4){0.f, 0.f, 0.f, 0.f};

  for (int c = 0; c < 24; ++c) {
    // (a) issue A(c+2) load
    float4 a2;
    if (c < 22) a2 = *(const float4*)(asrc + (c + 2) * 32);
    __builtin_amdgcn_sched_barrier(0);
    // (b) cvt + write A(c+1) into buf (c+1)&1
    if (c < 23) {
      uint2 wv; wv.x = cvt_pk_bf16(a1.x, a1.y); wv.y = cvt_pk_bf16(a1.z, a1.w);
      *(uint2*)(smem + 98304 + ((c + 1) & 1) * 4096 + abyte) = wv;
    }
    __builtin_amdgcn_sched_barrier(0);
    // (c) retire own W(c) DMA (keep A(c+2) in flight), drain LDS writes, barrier
    if (c < 22) asm volatile("s_waitcnt vmcnt(1)" ::: "memory");
    else        asm volatile("s_waitcnt vmcnt(0)" ::: "memory");
    asm volatile("s_waitcnt lgkmcnt(0)" ::: "memory");
    __builtin_amdgcn_s_barrier();
    __builtin_amdgcn_sched_barrier(0);
    // (d) stage W(c+1)
    if (c < 23) {
      const unsigned char* sW = wimg + (size_t)(c + 1) * PWCHUNK + t * 16;
      unsigned char* dW = smem + ((c + 1) & 1) * PWCHUNK + t * 16;
#pragma unroll
      for (int i = 0; i < 6; ++i) gl_lds16(sW + i * 8192, dW + i * 8192);
    }
    __builtin_amdgcn_sched_barrier(0);
    // (e) MFMA
    const unsigned char* WB = smem + (c & 1) * PWCHUNK;
    const unsigned char* AB = smem + 98304 + (c & 1) * 4096;
    bf16x8 af0 = *(const bf16x8*)(AB + afh[0]);
    bf16x8 af1 = *(const bf16x8*)(AB + afh[1]);
    __builtin_amdgcn_s_setprio(1);
#pragma unroll
    for (int ns = 0; ns < 12; ++ns) {
      int n = wn * 192 + ns * 16 + ln;
      bf16x8 bfrag = *(const bf16x8*)(WB + n * 64 + ((g ^ ((n >> 1) & 3)) << 4));
      acc[0][ns] = __builtin_amdgcn_mfma_f32_16x16x32_bf16(af0, bfrag, acc[0][ns], 0, 0, 0);
      acc[1][ns] = __builtin_amdgcn_mfma_f32_16x16x32_bf16(af1, bfrag, acc[1][ns], 0, 0, 0);
    }
    __builtin_amdgcn_s_setprio(0);
    a1 = a2;
  }

  // epilogue: bias + store (only this block's own rows -> in-place safe)
#pragma unroll
  for (int ns = 0; ns < 12; ++ns) {
    int col = wn * 192 + ns * 16 + ln;
    float pbv = pb[col];
#pragma unroll
    for (int sm = 0; sm < 2; ++sm)
#pragma unroll
      for (int r = 0; r < 4; ++r)
        dst[(row0 + wm * 32 + sm * 16 + 4 * g + r) * DM + col] = acc[sm][ns][r] + pbv;
  }
}

// ---------------- attn fallback (round-2 verified): used if ws too small ------
__global__ __launch_bounds__(512, 2) void attn_kernel_fb(
    const float* __restrict__ x, const float* __restrict__ qkv_w,
    const float* __restrict__ qkv_b, const float* __restrict__ edge_bias,
    const float* __restrict__ mask, float* __restrict__ out)
{
  __shared__ __align__(16) unsigned char smem[98304];
  const int t = threadIdx.x;
  const int lane = t & 63;
  const int w = t >> 6;
  const int g = lane >> 4;
  const int ln = lane & 15;
  const int wm = w & 3;
  const int wn = w >> 2;

  const int orig = blockIdx.x;
  const int wg = (orig & 7) * 768 + (orig >> 3);
  const int h = wg % 12;
  const int bn = wg / 12;

  const float* xw = x + (size_t)bn * (WT * DM);

  f32x4 acc[2][6];
#pragma unroll
  for (int i = 0; i < 2; ++i)
#pragma unroll
    for (int j = 0; j < 6; ++j) acc[i][j] = (f32x4){0.f, 0.f, 0.f, 0.f};

  float4 wreg[6], xreg[8];
#pragma unroll
  for (int q = 0; q < 6; ++q) {
    int fid = q * 512 + t;
    int j = fid >> 4, c4 = fid & 15;
    int sec = j >> 6, d = j & 63;
    wreg[q] = *(const float4*)(qkv_w + (size_t)(sec * DM + h * 64 + d) * DM + c4 * 4);
  }

  for (int c = 0; c < 12; ++c) {
    const int kc = c * 64;
#pragma unroll
    for (int sm = 0; sm < 2; ++sm)
#pragma unroll
      for (int ks = 0; ks < 2; ++ks) {
        int row = wm * 32 + sm * 16 + ln;
        const float* p = xw + (size_t)row * DM + kc + ks * 32 + g * 8;
        xreg[(sm * 2 + ks) * 2 + 0] = *(const float4*)p;
        xreg[(sm * 2 + ks) * 2 + 1] = *(const float4*)(p + 4);
      }
    unsigned char* WH = smem + (c & 1) * 49152;
    unsigned char* WL = WH + 24576;
#pragma unroll
    for (int q = 0; q < 6; ++q) {
      int fid = q * 512 + t;
      int j = fid >> 4, c4 = fid & 15;
      int byte = j * 128 + ((((c4 >> 1) ^ (j & 7))) << 4) + ((c4 & 1) << 3);
      float4 v = wreg[q];
      unsigned short h0, h1, h2, h3, l0, l1, l2, l3;
      bf_split(v.x, h0, l0); bf_split(v.y, h1, l1);
      bf_split(v.z, h2, l2); bf_split(v.w, h3, l3);
      uint2 hv, lv;
      hv.x = (unsigned)h0 | ((unsigned)h1 << 16); hv.y = (unsigned)h2 | ((unsigned)h3 << 16);
      lv.x = (unsigned)l0 | ((unsigned)l1 << 16); lv.y = (unsigned)l2 | ((unsigned)l3 << 16);
      *(uint2*)(WH + byte) = hv;
      *(uint2*)(WL + byte) = lv;
    }
    if (c < 11) {
#pragma unroll
      for (int q = 0; q < 6; ++q) {
        int fid = q * 512 + t;
        int j = fid >> 4, c4 = fid & 15;
        int sec = j >> 6, d = j & 63;
        wreg[q] = *(const float4*)(qkv_w + (size_t)(sec * DM + h * 64 + d) * DM + kc + 64 + c4 * 4);
      }
    }
    __syncthreads();
#pragma unroll
    for (int ks = 0; ks < 2; ++ks) {
      bf16x8 ah[2], al[2];
#pragma unroll
      for (int sm = 0; sm < 2; ++sm)
        split8(xreg[(sm * 2 + ks) * 2 + 0], xreg[(sm * 2 + ks) * 2 + 1], ah[sm], al[sm]);
#pragma unroll
      for (int ns = 0; ns < 6; ++ns) {
        int j = wn * 96 + ns * 16 + ln;
        int sw = j * 128 + (((ks * 4 + g) ^ (j & 7)) << 4);
        bf16x8 bh = *(const bf16x8*)(WH + sw);
        bf16x8 bl = *(const bf16x8*)(WL + sw);
#pragma unroll
        for (int sm = 0; sm < 2; ++sm) {
          acc[sm][ns] = __builtin_amdgcn_mfma_f32_16x16x32_bf16(ah[sm], bh, acc[sm][ns], 0, 0, 0);
          acc[sm][ns] = __builtin_amdgcn_mfma_f32_16x16x32_bf16(ah[sm], bl, acc[sm][ns], 0, 0, 0);
          acc[sm][ns] = __builtin_amdgcn_mfma_f32_16x16x32_bf16(al[sm], bh, acc[sm][ns], 0, 0, 0);
        }
      }
    }
  }
  __syncthreads();

#pragma unroll
  for (int sm = 0; sm < 2; ++sm)
#pragma unroll
    for (int ns = 0; ns < 6; ++ns) {
      int cc = wn * 96 + ns * 16 + ln;
      int sec = cc >> 6, dd = cc & 63;
      float bias = qkv_b[sec * DM + h * 64 + dd];
#pragma unroll
      for (int r = 0; r < 4; ++r) {
        int m = wm * 32 + sm * 16 + 4 * g + r;
        float val = acc[sm][ns][r] + bias;
        if (cc < 64) {
          val *= 0.125f;
          unsigned short hi, lo; bf_split(val, hi, lo);
          int byte = m * 128 + ((((dd >> 3) ^ (m & 7))) << 4) + ((dd & 7) << 1);
          *(unsigned short*)(smem + QH_OFF + byte) = hi;
          *(unsigned short*)(smem + QL_OFF + byte) = lo;
        } else if (cc < 128) {
          unsigned short hi, lo; bf_split(val, hi, lo);
          int byte = m * 128 + ((((dd >> 3) ^ (m & 7))) << 4) + ((dd & 7) << 1);
          *(unsigned short*)(smem + KH_OFF + byte) = hi;
          *(unsigned short*)(smem + KL_OFF + byte) = lo;
        } else {
          *(unsigned short*)(smem + VT_OFF + dd * 272 + m * 2) = bf_rne(val);
        }
      }
    }
  __syncthreads();

  const int mB = w * 16;
  f32x4 s2[8];
#pragma unroll
  for (int ns = 0; ns < 8; ++ns) s2[ns] = (f32x4){0.f, 0.f, 0.f, 0.f};
#pragma unroll
  for (int ks = 0; ks < 2; ++ks) {
    int arow = mB + ln;
    int abyte = arow * 128 + (((ks * 4 + g) ^ (arow & 7)) << 4);
    bf16x8 qh = *(const bf16x8*)(smem + QH_OFF + abyte);
    bf16x8 ql = *(const bf16x8*)(smem + QL_OFF + abyte);
#pragma unroll
    for (int ns = 0; ns < 8; ++ns) {
      int brow = ns * 16 + ln;
      int bbyte = brow * 128 + (((ks * 4 + g) ^ (brow & 7)) << 4);
      bf16x8 kh = *(const bf16x8*)(smem + KH_OFF + bbyte);
      bf16x8 kl = *(const bf16x8*)(smem + KL_OFF + bbyte);
      s2[ns] = __builtin_amdgcn_mfma_f32_16x16x32_bf16(qh, kh, s2[ns], 0, 0, 0);
      s2[ns] = __builtin_amdgcn_mfma_f32_16x16x32_bf16(qh, kl, s2[ns], 0, 0, 0);
      s2[ns] = __builtin_amdgcn_mfma_f32_16x16x32_bf16(ql, kh, s2[ns], 0, 0, 0);
    }
  }
  __syncthreads();

  const float* mk = mask + (size_t)(bn & 127) * (WT * WT);
  const float* eb = edge_bias + (size_t)h * (WT * WT);
#pragma unroll
  for (int r = 0; r < 4; ++r) {
    int m = mB + 4 * g + r;
    float sv[8];
#pragma unroll
    for (int ns = 0; ns < 8; ++ns) sv[ns] = s2[ns][r];
    float m1 = sv[0];
#pragma unroll
    for (int ns = 1; ns < 8; ++ns) m1 = fmaxf(m1, sv[ns]);
#pragma unroll
    for (int off = 1; off < 16; off <<= 1) m1 = fmaxf(m1, __shfl_xor(m1, off, 64));
    float e[8], sum1 = 0.f;
#pragma unroll
    for (int ns = 0; ns < 8; ++ns) { e[ns] = __expf(sv[ns] - m1); sum1 += e[ns]; }
#pragma unroll
    for (int off = 1; off < 16; off <<= 1) sum1 += __shfl_xor(sum1, off, 64);
    float thr = 0.5f * sum1;
    float tv[8];
#pragma unroll
    for (int ns = 0; ns < 8; ++ns) {
      int col = ns * 16 + ln;
      float mkv = mk[m * WT + col];
      float ebv = eb[m * WT + col];
      float keep = (e[ns] > thr) ? 0.f : 1.f;
      float val = sv[ns] * keep * mkv * ebv;
      tv[ns] = (val == 0.f) ? -10000.f : val;
    }
    float m2 = tv[0];
#pragma unroll
    for (int ns = 1; ns < 8; ++ns) m2 = fmaxf(m2, tv[ns]);
#pragma unroll
    for (int off = 1; off < 16; off <<= 1) m2 = fmaxf(m2, __shfl_xor(m2, off, 64));
    float e2[8], sum2 = 0.f;
#pragma unroll
    for (int ns = 0; ns < 8; ++ns) { e2[ns] = __expf(tv[ns] - m2); sum2 += e2[ns]; }
#pragma unroll
    for (int off = 1; off < 16; off <<= 1) sum2 += __shfl_xor(sum2, off, 64);
    float inv = 1.f / sum2;
#pragma unroll
    for (int ns = 0; ns < 8; ++ns)
      *(unsigned short*)(smem + P_OFF + m * 272 + (ns * 16 + ln) * 2) = bf_rne(e2[ns] * inv);
  }
  __syncthreads();

  f32x4 o4[4];
#pragma unroll
  for (int ns = 0; ns < 4; ++ns) o4[ns] = (f32x4){0.f, 0.f, 0.f, 0.f};
#pragma unroll
  for (int ks = 0; ks < 4; ++ks) {
    bf16x8 pa = *(const bf16x8*)(smem + P_OFF + (mB + ln) * 272 + ks * 64 + g * 16);
#pragma unroll
    for (int ns = 0; ns < 4; ++ns) {
      bf16x8 vb = *(const bf16x8*)(smem + VT_OFF + (ns * 16 + ln) * 272 + ks * 64 + g * 16);
      o4[ns] = __builtin_amdgcn_mfma_f32_16x16x32_bf16(pa, vb, o4[ns], 0, 0, 0);
    }
  }
#pragma unroll
  for (int ns = 0; ns < 4; ++ns)
#pragma unroll
    for (int r = 0; r < 4; ++r)
      out[(size_t)bn * (WT * DM) + (size_t)(mB + 4 * g + r) * DM + h * 64 + ns * 16 + ln] = o4[ns][r];
}

// ---------------- proj fallback: round-2/3 verified 64-row version ------------
#define PA_OFF 0
#define PW_OFF 98304

__global__ __launch_bounds__(512, 2) void proj_kernel_fb(
    const float* src, const float* __restrict__ pw,
    const float* __restrict__ pb, float* dst)
{
  __shared__ __align__(16) unsigned char smem[147456];
  const int t = threadIdx.x;
  const int lane = t & 63;
  const int w = t >> 6;
  const int g = lane >> 4;
  const int ln = lane & 15;
  const int wm = w & 1;
  const int wn = w >> 1;

  const int orig = blockIdx.x;
  const int wg = (orig & 7) * 128 + (orig >> 3);
  const size_t row0 = (size_t)wg * 64;

#pragma unroll
  for (int q = 0; q < 24; ++q) {
    int fid = q * 512 + t;
    int row = fid / 192, c4 = fid % 192;
    float4 v = *(const float4*)(src + (row0 + row) * DM + c4 * 4);
    int slot = c4 >> 1;
    int byte = row * 1536 + (((slot & ~7) | ((slot & 7) ^ (row & 7))) << 4) + ((c4 & 1) << 3);
    uint2 hv;
    hv.x = (unsigned)bf_rne(v.x) | ((unsigned)bf_rne(v.y) << 16);
    hv.y = (unsigned)bf_rne(v.z) | ((unsigned)bf_rne(v.w) << 16);
    *(uint2*)(smem + PA_OFF + byte) = hv;
  }

  f32x4 accp[2][12];
#pragma unroll
  for (int i = 0; i < 2; ++i)
#pragma unroll
    for (int j = 0; j < 12; ++j) accp[i][j] = (f32x4){0.f, 0.f, 0.f, 0.f};

  for (int c = 0; c < 24; ++c) {
    const int kc = c * 32;
    __syncthreads();
#pragma unroll
    for (int q = 0; q < 12; ++q) {
      int fid = q * 512 + t;
      int n = fid >> 3, c4 = fid & 7;
      float4 v = *(const float4*)(pw + (size_t)n * DM + kc + c4 * 4);
      int slot = (n & 1) * 4 + (c4 >> 1);
      int byte = (n >> 1) * 128 + ((slot ^ ((n >> 1) & 7)) << 4) + ((c4 & 1) << 3);
      uint2 hv;
      hv.x = (unsigned)bf_rne(v.x) | ((unsigned)bf_rne(v.y) << 16);
      hv.y = (unsigned)bf_rne(v.z) | ((unsigned)bf_rne(v.w) << 16);
      *(uint2*)(smem + PW_OFF + byte) = hv;
    }
    __syncthreads();
    bf16x8 af[2];
#pragma unroll
    for (int sm = 0; sm < 2; ++sm) {
      int row = wm * 32 + sm * 16 + ln;
      int slot = (kc >> 3) + g;
      int byte = row * 1536 + (((slot & ~7) | ((slot & 7) ^ (row & 7))) << 4);
      af[sm] = *(const bf16x8*)(smem + PA_OFF + byte);
    }
#pragma unroll
    for (int j = 0; j < 12; ++j) {
      int n = (wn * 12 + j) * 16 + ln;
      int slot = (n & 1) * 4 + g;
      bf16x8 bf_ = *(const bf16x8*)(smem + PW_OFF + (n >> 1) * 128 + ((slot ^ ((n >> 1) & 7)) << 4));
#pragma unroll
      for (int sm = 0; sm < 2; ++sm)
        accp[sm][j] = __builtin_amdgcn_mfma_f32_16x16x32_bf16(af[sm], bf_, accp[sm][j], 0, 0, 0);
    }
  }

#pragma unroll
  for (int j = 0; j < 12; ++j) {
    int col = (wn * 12 + j) * 16 + ln;
    float pbv = pb[col];
#pragma unroll
    for (int sm = 0; sm < 2; ++sm)
#pragma unroll
      for (int r = 0; r < 4; ++r)
        dst[(row0 + wm * 32 + sm * 16 + 4 * g + r) * DM + col] = accp[sm][j][r] + pbv;
  }
}

extern "C" void kernel_launch(void* const* d_in, const int* in_sizes, int n_in,
                              void* d_out, int out_size, void* d_ws, size_t ws_size,
                              hipStream_t stream) {
  const float* x         = (const float*)d_in[0];
  const float* qkv_w     = (const float*)d_in[1];
  const float* qkv_b     = (const float*)d_in[2];
  const float* proj_w    = (const float*)d_in[3];
  const float* proj_b    = (const float*)d_in[4];
  const float* edge_bias = (const float*)d_in[5];
  const float* mask      = (const float*)d_in[6];
  float* out = (float*)d_out;

  const bool p1 = (d_ws != nullptr) && (ws_size >= WS_W1);
  const bool p2 = (d_ws != nullptr) && (ws_size >= WS_W1 + WS_W2);
  unsigned char* wsW = (unsigned char*)d_ws;
  unsigned char* wsP = wsW + WS_W1;

  if (p1) {
    split_w_kernel<<<1728, 256, 0, stream>>>(qkv_w, wsW);
  }
  if (p2) {
    split_pw_kernel<<<576, 256, 0, stream>>>(proj_w, wsP);
  }
  if (p1) {
    attn_kernel_pre<<<NW * NH, 512, 0, stream>>>(x, wsW, qkv_b, edge_bias, mask, out);
  } else {
    attn_kernel_fb<<<NW * NH, 512, 0, stream>>>(x, qkv_w, qkv_b, edge_bias, mask, out);
  }
  if (p2) {
    proj_kernel_pre<<<1024, 512, 0, stream>>>(out, wsP, proj_b, out);
  } else {
    proj_kernel_fb<<<1024, 512, 0, stream>>>(out, proj_w, proj_b, out);
  }
}